// Round 10
// baseline (2330.841 us; speedup 1.0000x reference)
//
#include <hip/hip_runtime.h>
#include <hip/hip_fp16.h>

typedef _Float16 f16;
typedef _Float16 f16x2 __attribute__((ext_vector_type(2)));
typedef _Float16 f16x8 __attribute__((ext_vector_type(8)));
typedef float f32x4 __attribute__((ext_vector_type(4)));

#define DEV static __device__ __forceinline__

// LDS-only barrier — keeps global loads/stores in flight.
DEV void lds_barrier() {
  asm volatile("s_waitcnt lgkmcnt(0)" ::: "memory");
  __builtin_amdgcn_s_barrier();
  asm volatile("" ::: "memory");
}

// ---- VALU cross-lane helpers (no DS pipe) ----
template<int CTRL>
DEV float dpp_add(float x) {
  int y = __builtin_amdgcn_update_dpp(0, __builtin_bit_cast(int, x), CTRL, 0xf, 0xf, false);
  return x + __builtin_bit_cast(float, y);
}
template<int CTRL>
DEV f16x2 dpp_pkadd(f16x2 x) {
  int y = __builtin_amdgcn_update_dpp(0, __builtin_bit_cast(int, x), CTRL, 0xf, 0xf, false);
  return x + __builtin_bit_cast(f16x2, y);
}
DEV float pl32_add(float x) {  // x + x[lane^32]
  unsigned xi = __builtin_bit_cast(unsigned, x);
  auto r = __builtin_amdgcn_permlane32_swap(xi, xi, false, false);
  return __builtin_bit_cast(float, (unsigned)r[0]) + __builtin_bit_cast(float, (unsigned)r[1]);
}
DEV float swap16_add(float x) {  // x + x[lane^16]
#if __has_builtin(__builtin_amdgcn_permlane16_swap)
  unsigned xi = __builtin_bit_cast(unsigned, x);
  auto r = __builtin_amdgcn_permlane16_swap(xi, xi, false, false);
  return __builtin_bit_cast(float, (unsigned)r[0]) + __builtin_bit_cast(float, (unsigned)r[1]);
#else
  int y = __builtin_amdgcn_ds_swizzle(__builtin_bit_cast(int, x), 0x401F);
  return x + __builtin_bit_cast(float, y);
#endif
}

// ---------------------------------------------------------------- conv1
__global__ __launch_bounds__(256) void k_conv1(
    const float* __restrict__ in, const float* __restrict__ w,
    const float* __restrict__ bias, f16* __restrict__ out)
{
  int idx = blockIdx.x*256 + threadIdx.x;
  int co = idx & 63;
  int ow = (idx >> 6) % 40;
  int oh = ((idx >> 6) / 40) % 1024;
  int b  = idx / (64*40*1024);
  float acc = bias[co];
#pragma unroll
  for (int kh=0; kh<3; kh++) {
    int ih = oh*2 + kh;
    if (ih >= 2048) continue;
#pragma unroll
    for (int kw=0; kw<3; kw++) {
      int iw = ow*2 + kw;
      if (iw >= 80) continue;
      acc += in[(b*2048 + ih)*80 + iw] * w[(kh*3+kw)*64 + co];
    }
  }
  out[idx] = (f16)fmaxf(acc, 0.f);
}

// ---------------------------------------------------------------- weight convert+transpose
__global__ __launch_bounds__(256) void k_wcvt(
    const float* __restrict__ w, f16* __restrict__ wt)
{
  int idx = blockIdx.x*256 + threadIdx.x;
  if (idx >= 38912) return;
  f16 v = (f16)0.f;
  if (idx < 38400) {
    int n = idx / 600, k = idx % 600;
    if (k < 576) v = (f16)w[k*64 + n];
  }
  wt[idx] = v;
}

// ---------------------------------------------------------------- conv2 as implicit GEMM (MFMA fp16)
__global__ __launch_bounds__(256) void k_conv2m(
    const f16* __restrict__ x1f, const f16* __restrict__ wt,
    const float* __restrict__ bias, float* __restrict__ out)
{
  __shared__ f16 Bt[38912];
  const int tid = threadIdx.x;
  for (int it = 0; it < 19; ++it) {
    const f16* g = wt + it*2048 + tid*8;
    f16* l = Bt + it*2048 + tid*8;
    __builtin_amdgcn_global_load_lds(
        (const __attribute__((address_space(1))) void*)g,
        (__attribute__((address_space(3))) void*)l, 16, 0, 0);
  }
  __syncthreads();

  const int wave = tid >> 6, l = tid & 63;
  const int lrow = l & 15, lk = l >> 4;
  const int m0 = blockIdx.x*128 + wave*32;

  const int mA = m0 + lrow, mB = m0 + 16 + lrow;
  int bA = mA/10240, rA = mA%10240, ohA = rA/20, owA = rA%20;
  int bB = mB/10240, rB = mB%10240, ohB = rB/20, owB = rB%20;
  const f16* pA = x1f + ((size_t)((bA*1024 + ohA*2)*40 + owA*2))*64;
  const f16* pB = x1f + ((size_t)((bB*1024 + ohB*2)*40 + owB*2))*64;

  f32x4 acc[2][4];
#pragma unroll
  for (int i=0;i<2;i++)
#pragma unroll
    for (int j=0;j<4;j++) acc[i][j] = (f32x4){0.f,0.f,0.f,0.f};

  const f16x8 zero8 = {};
#pragma unroll
  for (int kk=0; kk<18; ++kk) {
    const int tap = kk >> 1;
    const int kh = tap/3, kw = tap%3;
    const int ci0 = ((kk&1)<<5) + lk*8;
    const int off = (kh*40 + kw)*64 + ci0;
    const bool okA = (ohA*2+kh < 1024) && (owA*2+kw < 40);
    const bool okB = (ohB*2+kh < 1024) && (owB*2+kw < 40);
    f16x8 a0 = okA ? *(const f16x8*)(pA + off) : zero8;
    f16x8 a1 = okB ? *(const f16x8*)(pB + off) : zero8;
#pragma unroll
    for (int nf=0; nf<4; ++nf) {
      f16x8 bb = *(const f16x8*)&Bt[(nf*16 + lrow)*600 + kk*32 + lk*8];
      acc[0][nf] = __builtin_amdgcn_mfma_f32_16x16x32_f16(a0, bb, acc[0][nf], 0,0,0);
      acc[1][nf] = __builtin_amdgcn_mfma_f32_16x16x32_f16(a1, bb, acc[1][nf], 0,0,0);
    }
  }
#pragma unroll
  for (int nf=0; nf<4; ++nf) {
    const int n = nf*16 + lrow;
    const float bi = bias[n];
#pragma unroll
    for (int mf=0; mf<2; ++mf)
#pragma unroll
      for (int r=0; r<4; ++r) {
        int mrow = m0 + mf*16 + lk*4 + r;
        out[(size_t)mrow*64 + n] = fmaxf(acc[mf][nf][r] + bi, 0.f);
      }
  }
}

// ---------------------------------------------------------------- proj
__global__ __launch_bounds__(256) void k_proj(
    const float* __restrict__ x, const float* __restrict__ pw,
    const float* __restrict__ pb, float* __restrict__ out)
{
  int bt = blockIdx.x;
  int tid = threadIdx.x;
  int j = tid >> 4;
  int l = tid & 15;
  const float* xr = x + (size_t)bt*1280;
  float s = 0.f;
  for (int k=0; k<80; k++) {
    int f = l + 16*k;
    s += xr[f] * pw[f*16 + j];
  }
  s += __shfl_xor(s, 1, 16); s += __shfl_xor(s, 2, 16);
  s += __shfl_xor(s, 4, 16); s += __shfl_xor(s, 8, 16);
  if (l == 0) out[bt*16 + j] = s + pb[j];
}

// ------------------------------------------- primary caps
__global__ __launch_bounds__(128) void k_primary(
    const float* __restrict__ emb0,
    const float* __restrict__ w0, const float* __restrict__ b0,
    const float* __restrict__ w1, const float* __restrict__ b1,
    const float* __restrict__ g, const float* __restrict__ be,
    const int* __restrict__ lens, float* __restrict__ out)
{
  int bt = blockIdx.x;
  int b = bt >> 9, t = bt & 511;
  int tid = threadIdx.x;
  int c = tid & 7, j = tid >> 3;
  __shared__ float rows[3][16];
  __shared__ float red[4];
  if (tid < 48) {
    int kh = tid / 16, jj = tid % 16;
    int ts = t + kh - 1;
    rows[kh][jj] = (ts >= 0 && ts < 512) ? emb0[(b*512+ts)*16 + jj] : 0.f;
  }
  __syncthreads();
  float a0 = b0[c], a1 = b1[c];
#pragma unroll
  for (int kh=0; kh<3; kh++)
#pragma unroll
    for (int kw=0; kw<3; kw++) {
      int jj = j + kw - 1;
      if (jj < 0 || jj >= 16) continue;
      float xv = rows[kh][jj];
      a0 += xv * w0[(kh*3+kw)*8 + c];
      a1 += xv * w1[(kh*3+kw)*8 + c];
    }
  float e = fmaxf(a0, a1);
  int valid = (lens[b] + 3) >> 2;
  if (t >= valid) e = 0.f;
  float sq = e*e;
  sq += __shfl_xor(sq, 1, 8); sq += __shfl_xor(sq, 2, 8); sq += __shfl_xor(sq, 4, 8);
  float val = e * (sq / (1.f + sq)) * rsqrtf(sq + 1e-9f);
  float s1 = val, s2 = val*val;
#pragma unroll
  for (int m=1;m<64;m<<=1){ s1 += __shfl_xor(s1,m,64); s2 += __shfl_xor(s2,m,64); }
  if ((tid & 63) == 0){ red[(tid>>6)*2] = s1; red[(tid>>6)*2+1] = s2; }
  __syncthreads();
  float S1 = red[0]+red[2], S2 = red[1]+red[3];
  float mean = S1/128.f;
  float var  = S2/128.f - mean*mean;
  out[(size_t)bt*128 + tid] = (val-mean)*rsqrtf(var+1e-3f)*g[tid] + be[tid];
}

// ---------------------------------------------------------------- generic LN over 128
__global__ __launch_bounds__(128) void k_ln128(
    const float* __restrict__ in, const float* __restrict__ g,
    const float* __restrict__ be, float* __restrict__ out)
{
  int bt = blockIdx.x, tid = threadIdx.x;
  float x = in[(size_t)bt*128 + tid];
  __shared__ float red[4];
  float s1 = x, s2 = x*x;
#pragma unroll
  for (int m=1;m<64;m<<=1){ s1 += __shfl_xor(s1,m,64); s2 += __shfl_xor(s2,m,64); }
  if ((tid & 63) == 0){ red[(tid>>6)*2] = s1; red[(tid>>6)*2+1] = s2; }
  __syncthreads();
  float S1 = red[0]+red[2], S2 = red[1]+red[3];
  float mean = S1/128.f;
  float var  = S2/128.f - mean*mean;
  out[(size_t)bt*128 + tid] = (x-mean)*rsqrtf(var+1e-3f)*g[tid] + be[tid];
}

// ---------------------------------------------------------------- u_hat precompute
template<int CO, int CD>
__global__ __launch_bounds__(256) void k_uhat(
    const float* __restrict__ src, const float* __restrict__ W,
    const float* __restrict__ Bs, f16* __restrict__ out)
{
  constexpr int NP = 80*CO;
  int wid = __builtin_amdgcn_readfirstlane(blockIdx.x*4 + (threadIdx.x >> 6));
  int lane = threadIdx.x & 63;
  int n   = wid % 80;
  int btc = wid / 80;
  int bt = btc*64 + lane;
  int b = bt >> 9, t = bt & 511;
  int k = n >> 4, i = n & 15;
  int ts = t + k - 2;
  float x[8];
  if (ts >= 0 && ts < 512) {
    const float* xr = src + ((size_t)(b*512+ts)*16 + i)*8;
    f32x4 x0 = *(const f32x4*)xr;
    f32x4 x1 = *(const f32x4*)(xr+4);
#pragma unroll
    for (int q=0;q<4;q++){ x[q]=x0[q]; x[4+q]=x1[q]; }
  } else {
#pragma unroll
    for (int q=0;q<8;q++) x[q]=0.f;
  }
  const float* Wn = W  + (size_t)n*CO*CD*8;
  const float* Bn = Bs + (size_t)n*CO*CD;
  for (int o=0; o<CO; o++) {
    alignas(16) f16 res[CD];
#pragma unroll
    for (int p=0;p<CD;p++) {
      float a = Bn[o*CD+p];
#pragma unroll
      for (int q=0;q<8;q++) a += Wn[(o*CD+p)*8+q]*x[q];
      res[p] = (f16)a;
    }
    f16* op = out + ((size_t)bt*NP + (size_t)n*CO + o)*CD;
    *(uint4*)op = *(const uint4*)res;
    if constexpr (CD==16) *((uint4*)op+1) = *((const uint4*)res+1);
  }
}

// ---------------------------------------------------------------- routing scan v9
// Wave-owns-o structure: each wave owns 4 o's (ol=lane>>4), its 16 n-lanes × 5
// slots cover ALL 80 n. PV n-reduce = 4 in-wave DPP row_ror hops on packed f16x2
// (no part/smat LDS transposes, v stays in registers). Only cross-wave datum:
// softmax denominators sm[n] (80 f32) via ds_add_f32 into a 3-phase rotating
// LDS buffer -> ONE barrier per step (zero-phase 2 steps ahead, race-free).
// Softmax: exp2 with v pre-scaled by log2e; no max-subtract (|logit| <~ 12).
template<int CO, int CD, bool MASK>
__global__ __launch_bounds__(CO*16, 1) void k_scan9(
    const f16* __restrict__ uh, float* __restrict__ vseq, int T)
{
  constexpr int NP = 80*CO;
  constexpr int QN = CO*CD;
  constexpr int NV = CD/8;       // 2 (L1) / 1 (L0)
  constexpr int P2 = CD/2;

  __shared__ float smb[3][96];   // denominators, 3-phase

  const int tid  = threadIdx.x;
  const int lane = tid & 63;
  const int wv   = tid >> 6;
  const int nl   = lane & 15;    // n-lane within o-group
  const int ol   = lane >> 4;    // 0..3
  const int o    = wv*4 + ol;

  const int b = blockIdx.x;
  const f16* __restrict__ ubase = uh + (size_t)b*T*NP*CD;
  float* __restrict__ vb = vseq + (size_t)b*T*QN;

  unsigned uoff[5];
#pragma unroll
  for (int s=0;s<5;s++) uoff[s] = (unsigned)((nl + 16*s)*CO + o)*CD;

  for (int i=tid; i<3*96; i+=CO*16) (&smb[0][0])[i] = 0.f;

  f16x2 vh[P2];
#pragma unroll
  for (int r=0;r<P2;r++) vh[r] = (f16x2){(f16)0,(f16)0};

  f16x8 UA[5][NV], UB[5][NV];
  int sp = 0;

#define LOADU9(U, PTR) do {                                                  \
  _Pragma("unroll") for (int s_=0; s_<5; ++s_)                               \
  _Pragma("unroll") for (int q_=0; q_<NV; ++q_)                              \
    U[s_][q_] = *(const f16x8*)((PTR) + uoff[s_] + q_*8);                    \
} while(0)

#define STEP9(U, TT) do {                                                    \
  /* logits -> ex (exp2; vh pre-scaled by log2e) */                          \
  float ex_[5];                                                              \
  _Pragma("unroll") for (int s_=0; s_<5; ++s_) {                             \
    float a_ = 0.f;                                                          \
    _Pragma("unroll") for (int q_=0; q_<NV; ++q_) {                          \
      const f16x2* u2_ = (const f16x2*)&U[s_][q_];                           \
      _Pragma("unroll") for (int z_=0; z_<4; ++z_)                           \
        a_ = __builtin_amdgcn_fdot2(u2_[z_], vh[q_*4+z_], a_, false);        \
    }                                                                        \
    float e_ = __builtin_amdgcn_exp2f(a_);                                   \
    if (MASK && o == 0) e_ = 0.f;                                            \
    ex_[s_] = e_;                                                            \
  }                                                                          \
  /* denominator partial over the wave's 4 o's, then LDS atomic */           \
  _Pragma("unroll") for (int s_=0; s_<5; ++s_) {                             \
    float d_ = swap16_add(ex_[s_]);                                          \
    d_ = pl32_add(d_);                                                       \
    if (ol == 0) atomicAdd(&smb[sp][nl + 16*s_], d_);                        \
  }                                                                          \
  lds_barrier();                                                             \
  { int zz_ = sp + 2; if (zz_ >= 3) zz_ -= 3;                                \
    if (tid < 80) smb[zz_][tid] = 0.f; }                                     \
  /* c = ex / sm[n]; pack to f16x2 */                                        \
  f16x2 c2_[5];                                                              \
  _Pragma("unroll") for (int s_=0; s_<5; ++s_) {                             \
    float c_ = ex_[s_] * __builtin_amdgcn_rcpf(smb[sp][nl + 16*s_]);         \
    f16 ch_ = (f16)c_;                                                       \
    c2_[s_] = (f16x2){ch_, ch_};                                             \
  }                                                                          \
  /* PV: packed fma, then in-wave 16-lane DPP reduce */                      \
  f16x2 pp2_[P2];                                                            \
  _Pragma("unroll") for (int r_=0; r_<P2; ++r_) pp2_[r_] = (f16x2){(f16)0,(f16)0}; \
  _Pragma("unroll") for (int s_=0; s_<5; ++s_) {                             \
    const f16x2* u2_ = (const f16x2*)&U[s_][0];                              \
    _Pragma("unroll") for (int r_=0; r_<P2; ++r_)                            \
      pp2_[r_] += u2_[r_] * c2_[s_];                                         \
  }                                                                          \
  _Pragma("unroll") for (int r_=0; r_<P2; ++r_) {                            \
    pp2_[r_] = dpp_pkadd<0x121>(pp2_[r_]);                                   \
    pp2_[r_] = dpp_pkadd<0x122>(pp2_[r_]);                                   \
    pp2_[r_] = dpp_pkadd<0x124>(pp2_[r_]);                                   \
    pp2_[r_] = dpp_pkadd<0x128>(pp2_[r_]);                                   \
  }                                                                          \
  /* squash (replicated per lane) */                                         \
  float sq_ = 0.f;                                                           \
  _Pragma("unroll") for (int r_=0; r_<P2; ++r_)                              \
    sq_ = __builtin_amdgcn_fdot2(pp2_[r_], pp2_[r_], sq_, false);            \
  float f_ = sq_ * __builtin_amdgcn_rcpf(1.f + sq_) * rsqrtf(sq_ + 1e-9f);   \
  if (nl == 0) {                                                             \
    float vn_[CD];                                                           \
    _Pragma("unroll") for (int r_=0; r_<P2; ++r_) {                          \
      vn_[2*r_]   = (float)pp2_[r_][0] * f_;                                 \
      vn_[2*r_+1] = (float)pp2_[r_][1] * f_;                                 \
    }                                                                        \
    float* orow_ = vb + (size_t)(TT)*QN + o*CD;                              \
    _Pragma("unroll") for (int p_=0; p_<CD; p_+=4) {                         \
      f32x4 w4_ = { vn_[p_], vn_[p_+1], vn_[p_+2], vn_[p_+3] };              \
      *(f32x4*)(orow_ + p_) = w4_;                                           \
    }                                                                        \
  }                                                                          \
  /* next-step v (packed, pre-scaled by log2e) */                            \
  { f16 fh_ = (f16)(f_ * 1.44269504f);                                       \
    f16x2 f2_ = (f16x2){fh_, fh_};                                           \
    _Pragma("unroll") for (int r_=0; r_<P2; ++r_) vh[r_] = pp2_[r_] * f2_; } \
  sp = sp + 1; if (sp >= 3) sp = 0;                                          \
} while(0)

  const size_t ST = (size_t)NP*CD;
  const f16* pcur = ubase;
  LOADU9(UA, pcur);
  lds_barrier();                     // smb zero-init visible
  for (int t=0; t<T; t+=2) {
    LOADU9(UB, pcur + ST);           // tile t+1
    STEP9(UA, t);
    LOADU9(UA, pcur + 2*ST);         // tile t+2 (tail overread stays in ws)
    STEP9(UB, t+1);
    pcur += 2*ST;
  }
#undef LOADU9
#undef STEP9
}

// ---------------------------------------------------------------- final: LN512 -> length -> LN32
__global__ __launch_bounds__(512) void k_final(
    const float* __restrict__ v1,
    const float* __restrict__ g1, const float* __restrict__ b1,
    const float* __restrict__ g2, const float* __restrict__ b2,
    float* __restrict__ out)
{
  int bt = blockIdx.x;
  int tid = threadIdx.x;
  float x = v1[(size_t)bt*512 + tid];
  __shared__ float red[16];
  __shared__ float Ls[32];
  float s1 = x, s2 = x*x;
#pragma unroll
  for (int m=1;m<64;m<<=1){ s1 += __shfl_xor(s1,m,64); s2 += __shfl_xor(s2,m,64); }
  if ((tid & 63) == 0){ red[(tid>>6)*2] = s1; red[(tid>>6)*2+1] = s2; }
  __syncthreads();
  float S1 = 0.f, S2 = 0.f;
#pragma unroll
  for (int i=0;i<8;i++){ S1 += red[2*i]; S2 += red[2*i+1]; }
  float mean = S1/512.f, var = S2/512.f - mean*mean;
  float y = (x-mean)*rsqrtf(var+1e-3f)*g1[tid] + b1[tid];
  float ss = y*y;
  ss += __shfl_xor(ss,1,16); ss += __shfl_xor(ss,2,16);
  ss += __shfl_xor(ss,4,16); ss += __shfl_xor(ss,8,16);
  float L = sqrtf(ss + 1e-9f);
  if ((tid & 15) == 0) Ls[tid >> 4] = L;
  __syncthreads();
  if (tid < 32) {
    float l = Ls[tid];
    float t1 = l, t2 = l*l;
#pragma unroll
    for (int m=1;m<32;m<<=1){ t1 += __shfl_xor(t1,m,32); t2 += __shfl_xor(t2,m,32); }
    float mn = t1/32.f, vr = t2/32.f - mn*mn;
    out[(size_t)bt*32 + tid] = (l-mn)*rsqrtf(vr+1e-3f)*g2[tid] + b2[tid];
  }
}

// ---------------------------------------------------------------- workspace layout
static const size_t OFF_X1F   = 0;            // 20,971,520 B f16 [4,1024,40,64]
static const size_t OFF_WT16  = 20971520;     //     77,824 B f16 [64][600]
static const size_t OFF_X2    = 21049344;     // 10,485,760 B f32 [4,512,20,64]
static const size_t OFF_EMB0  = 31535104;     //    131,072 B f32 [4,512,16]
static const size_t OFF_UH0   = 31666176;     // 41,943,040 B f16 [4,512,1280,8]
static const size_t OFF_UH1   = 0;            // 167,772,160 B f16 [4,512,2560,16]
static const size_t OFF_EMBLN = 167772160;    //  1,048,576 B f32 (dead before scan0)
static const size_t OFF_V0    = 167772160;    //  1,048,576 B f32 (reuses EMBLN slot)
static const size_t OFF_V0LN  = 168820736;    //  1,048,576 B f32
static const size_t OFF_V1    = 169869312;    //  4,194,304 B f32 [4,512,32,16]
static const size_t WS_NEED   = 174063616;

extern "C" void kernel_launch(void* const* d_in, const int* in_sizes, int n_in,
                              void* d_out, int out_size, void* d_ws, size_t ws_size,
                              hipStream_t stream) {
  (void)in_sizes; (void)n_in; (void)out_size;
  if (ws_size < WS_NEED) return;

  const float* inputs = (const float*)d_in[0];
  const int*   lens   = (const int*)d_in[1];
  const float* c1w=(const float*)d_in[2],  *c1b=(const float*)d_in[3];
  const float* c2w=(const float*)d_in[4],  *c2b=(const float*)d_in[5];
  const float* pw =(const float*)d_in[6],  *pb =(const float*)d_in[7];
  const float* e0w=(const float*)d_in[8],  *e0b=(const float*)d_in[9];
  const float* e1w=(const float*)d_in[10], *e1b=(const float*)d_in[11];
  const float* lnig=(const float*)d_in[12],*lnib=(const float*)d_in[13];
  const float* W0=(const float*)d_in[14],  *B0=(const float*)d_in[15];
  const float* W1=(const float*)d_in[16],  *B1=(const float*)d_in[17];
  const float* lnm0g=(const float*)d_in[18],*lnm0b=(const float*)d_in[19];
  const float* lnm1g=(const float*)d_in[20],*lnm1b=(const float*)d_in[21];
  const float* lnog=(const float*)d_in[22], *lnob=(const float*)d_in[23];

  char* ws = (char*)d_ws;
  f16*   x1f   = (f16*)  (ws + OFF_X1F);
  f16*   wt16  = (f16*)  (ws + OFF_WT16);
  float* x2    = (float*)(ws + OFF_X2);
  float* emb0  = (float*)(ws + OFF_EMB0);
  f16*   uh0   = (f16*)  (ws + OFF_UH0);
  f16*   uh1   = (f16*)  (ws + OFF_UH1);
  float* embln = (float*)(ws + OFF_EMBLN);
  float* v0    = (float*)(ws + OFF_V0);
  float* v0ln  = (float*)(ws + OFF_V0LN);
  float* v1    = (float*)(ws + OFF_V1);

  k_conv1<<<40960, 256, 0, stream>>>(inputs, c1w, c1b, x1f);
  k_wcvt <<<152, 256, 0, stream>>>(c2w, wt16);
  k_conv2m<<<320, 256, 0, stream>>>(x1f, wt16, c2b, x2);
  k_proj <<<2048, 256, 0, stream>>>(x2, pw, pb, emb0);
  k_primary<<<2048, 128, 0, stream>>>(emb0, e0w, e0b, e1w, e1b, lnig, lnib, lens, embln);
  k_uhat<16,8><<<640, 256, 0, stream>>>(embln, W0, B0, uh0);
  k_scan9<16,8,false><<<4, 256, 0, stream>>>(uh0, v0, 512);
  k_ln128<<<2048, 128, 0, stream>>>(v0, lnm0g, lnm0b, v0ln);
  k_uhat<32,16><<<640, 256, 0, stream>>>(v0ln, W1, B1, uh1);
  k_scan9<32,16,true><<<4, 512, 0, stream>>>(uh1, v1, 512);
  k_final<<<2048, 512, 0, stream>>>(v1, lnm1g, lnm1b, lnog, lnob, (float*)d_out);
}

// Round 11
// 2183.862 us; speedup vs baseline: 1.0673x; 1.0673x over previous
//
#include <hip/hip_runtime.h>
#include <hip/hip_fp16.h>

typedef _Float16 f16;
typedef _Float16 f16x2 __attribute__((ext_vector_type(2)));
typedef _Float16 f16x8 __attribute__((ext_vector_type(8)));
typedef float f32x4 __attribute__((ext_vector_type(4)));

#define DEV static __device__ __forceinline__

// LDS-only barrier — keeps global loads/stores in flight.
DEV void lds_barrier() {
  asm volatile("s_waitcnt lgkmcnt(0)" ::: "memory");
  __builtin_amdgcn_s_barrier();
  asm volatile("" ::: "memory");
}

// ---- VALU cross-lane reduction helpers (no DS pipe) ----
template<int CTRL>
DEV float dpp_add(float x) {
  int y = __builtin_amdgcn_update_dpp(0, __builtin_bit_cast(int, x), CTRL, 0xf, 0xf, false);
  return x + __builtin_bit_cast(float, y);
}
template<int CTRL>
DEV float dpp_get(float x) {
  int y = __builtin_amdgcn_update_dpp(0, __builtin_bit_cast(int, x), CTRL, 0xf, 0xf, false);
  return __builtin_bit_cast(float, y);
}
DEV float pl32_add(float x) {  // x + x[lane^32]
  unsigned xi = __builtin_bit_cast(unsigned, x);
  auto r = __builtin_amdgcn_permlane32_swap(xi, xi, false, false);
  return __builtin_bit_cast(float, (unsigned)r[0]) + __builtin_bit_cast(float, (unsigned)r[1]);
}
DEV float swap16_add(float x) {  // x + x[lane^16]
#if __has_builtin(__builtin_amdgcn_permlane16_swap)
  unsigned xi = __builtin_bit_cast(unsigned, x);
  auto r = __builtin_amdgcn_permlane16_swap(xi, xi, false, false);
  return __builtin_bit_cast(float, (unsigned)r[0]) + __builtin_bit_cast(float, (unsigned)r[1]);
#else
  int y = __builtin_amdgcn_ds_swizzle(__builtin_bit_cast(int, x), 0x401F);
  return x + __builtin_bit_cast(float, y);
#endif
}

// ---------------------------------------------------------------- conv1
__global__ __launch_bounds__(256) void k_conv1(
    const float* __restrict__ in, const float* __restrict__ w,
    const float* __restrict__ bias, f16* __restrict__ out)
{
  int idx = blockIdx.x*256 + threadIdx.x;
  int co = idx & 63;
  int ow = (idx >> 6) % 40;
  int oh = ((idx >> 6) / 40) % 1024;
  int b  = idx / (64*40*1024);
  float acc = bias[co];
#pragma unroll
  for (int kh=0; kh<3; kh++) {
    int ih = oh*2 + kh;
    if (ih >= 2048) continue;
#pragma unroll
    for (int kw=0; kw<3; kw++) {
      int iw = ow*2 + kw;
      if (iw >= 80) continue;
      acc += in[(b*2048 + ih)*80 + iw] * w[(kh*3+kw)*64 + co];
    }
  }
  out[idx] = (f16)fmaxf(acc, 0.f);
}

// ---------------------------------------------------------------- weight convert+transpose (conv2)
__global__ __launch_bounds__(256) void k_wcvt(
    const float* __restrict__ w, f16* __restrict__ wt)
{
  int idx = blockIdx.x*256 + threadIdx.x;
  if (idx >= 38912) return;
  f16 v = (f16)0.f;
  if (idx < 38400) {
    int n = idx / 600, k = idx % 600;
    if (k < 576) v = (f16)w[k*64 + n];
  }
  wt[idx] = v;
}

// ---------------------------------------------------------------- proj weight transpose: pw [1280][16] -> pwT f16 [16][1280]
__global__ __launch_bounds__(256) void k_wcvtp(
    const float* __restrict__ pw, f16* __restrict__ pwT)
{
  int idx = blockIdx.x*256 + threadIdx.x;
  if (idx >= 20480) return;
  int j = idx / 1280, f = idx % 1280;
  pwT[idx] = (f16)pw[f*16 + j];
}

// ---------------------------------------------------------------- conv2 as implicit GEMM (MFMA fp16) -> f16 out
__global__ __launch_bounds__(256) void k_conv2m(
    const f16* __restrict__ x1f, const f16* __restrict__ wt,
    const float* __restrict__ bias, f16* __restrict__ out)
{
  __shared__ f16 Bt[38912];
  const int tid = threadIdx.x;
  for (int it = 0; it < 19; ++it) {
    const f16* g = wt + it*2048 + tid*8;
    f16* l = Bt + it*2048 + tid*8;
    __builtin_amdgcn_global_load_lds(
        (const __attribute__((address_space(1))) void*)g,
        (__attribute__((address_space(3))) void*)l, 16, 0, 0);
  }
  __syncthreads();

  const int wave = tid >> 6, l = tid & 63;
  const int lrow = l & 15, lk = l >> 4;
  const int m0 = blockIdx.x*128 + wave*32;

  const int mA = m0 + lrow, mB = m0 + 16 + lrow;
  int bA = mA/10240, rA = mA%10240, ohA = rA/20, owA = rA%20;
  int bB = mB/10240, rB = mB%10240, ohB = rB/20, owB = rB%20;
  const f16* pA = x1f + ((size_t)((bA*1024 + ohA*2)*40 + owA*2))*64;
  const f16* pB = x1f + ((size_t)((bB*1024 + ohB*2)*40 + owB*2))*64;

  f32x4 acc[2][4];
#pragma unroll
  for (int i=0;i<2;i++)
#pragma unroll
    for (int j=0;j<4;j++) acc[i][j] = (f32x4){0.f,0.f,0.f,0.f};

  const f16x8 zero8 = {};
#pragma unroll
  for (int kk=0; kk<18; ++kk) {
    const int tap = kk >> 1;
    const int kh = tap/3, kw = tap%3;
    const int ci0 = ((kk&1)<<5) + lk*8;
    const int off = (kh*40 + kw)*64 + ci0;
    const bool okA = (ohA*2+kh < 1024) && (owA*2+kw < 40);
    const bool okB = (ohB*2+kh < 1024) && (owB*2+kw < 40);
    f16x8 a0 = okA ? *(const f16x8*)(pA + off) : zero8;
    f16x8 a1 = okB ? *(const f16x8*)(pB + off) : zero8;
#pragma unroll
    for (int nf=0; nf<4; ++nf) {
      f16x8 bb = *(const f16x8*)&Bt[(nf*16 + lrow)*600 + kk*32 + lk*8];
      acc[0][nf] = __builtin_amdgcn_mfma_f32_16x16x32_f16(a0, bb, acc[0][nf], 0,0,0);
      acc[1][nf] = __builtin_amdgcn_mfma_f32_16x16x32_f16(a1, bb, acc[1][nf], 0,0,0);
    }
  }
#pragma unroll
  for (int nf=0; nf<4; ++nf) {
    const int n = nf*16 + lrow;
    const float bi = bias[n];
#pragma unroll
    for (int mf=0; mf<2; ++mf)
#pragma unroll
      for (int r=0; r<4; ++r) {
        int mrow = m0 + mf*16 + lk*4 + r;
        out[(size_t)mrow*64 + n] = (f16)fmaxf(acc[mf][nf][r] + bi, 0.f);
      }
  }
}

// ---------------------------------------------------------------- proj as MFMA GEMM
// x2f f16 [2048][1280] @ pwT f16 [16][1280] -> emb0 f32 [2048][16]
__global__ __launch_bounds__(256) void k_projm(
    const f16* __restrict__ x2f, const f16* __restrict__ pwT,
    const float* __restrict__ pb, float* __restrict__ out)
{
  const int tid = threadIdx.x;
  const int wave = tid >> 6, l = tid & 63;
  const int lrow = l & 15, lk = l >> 4;
  const int m0 = (blockIdx.x*4 + wave)*16;
  const f16* pA = x2f + (size_t)(m0 + lrow)*1280 + lk*8;
  const f16* pB = pwT + (size_t)lrow*1280 + lk*8;
  f32x4 acc = {0.f,0.f,0.f,0.f};
#pragma unroll 4
  for (int k=0; k<40; ++k) {
    f16x8 a  = *(const f16x8*)(pA + k*32);
    f16x8 bb = *(const f16x8*)(pB + k*32);
    acc = __builtin_amdgcn_mfma_f32_16x16x32_f16(a, bb, acc, 0,0,0);
  }
#pragma unroll
  for (int r=0; r<4; ++r) {
    int row = m0 + lk*4 + r;
    out[(size_t)row*16 + lrow] = acc[r] + pb[lrow];
  }
}

// ------------------------------------------- primary caps
__global__ __launch_bounds__(128) void k_primary(
    const float* __restrict__ emb0,
    const float* __restrict__ w0, const float* __restrict__ b0,
    const float* __restrict__ w1, const float* __restrict__ b1,
    const float* __restrict__ g, const float* __restrict__ be,
    const int* __restrict__ lens, float* __restrict__ out)
{
  int bt = blockIdx.x;
  int b = bt >> 9, t = bt & 511;
  int tid = threadIdx.x;
  int c = tid & 7, j = tid >> 3;
  __shared__ float rows[3][16];
  __shared__ float red[4];
  if (tid < 48) {
    int kh = tid / 16, jj = tid % 16;
    int ts = t + kh - 1;
    rows[kh][jj] = (ts >= 0 && ts < 512) ? emb0[(b*512+ts)*16 + jj] : 0.f;
  }
  __syncthreads();
  float a0 = b0[c], a1 = b1[c];
#pragma unroll
  for (int kh=0; kh<3; kh++)
#pragma unroll
    for (int kw=0; kw<3; kw++) {
      int jj = j + kw - 1;
      if (jj < 0 || jj >= 16) continue;
      float xv = rows[kh][jj];
      a0 += xv * w0[(kh*3+kw)*8 + c];
      a1 += xv * w1[(kh*3+kw)*8 + c];
    }
  float e = fmaxf(a0, a1);
  int valid = (lens[b] + 3) >> 2;
  if (t >= valid) e = 0.f;
  float sq = e*e;
  sq += __shfl_xor(sq, 1, 8); sq += __shfl_xor(sq, 2, 8); sq += __shfl_xor(sq, 4, 8);
  float val = e * (sq / (1.f + sq)) * rsqrtf(sq + 1e-9f);
  float s1 = val, s2 = val*val;
#pragma unroll
  for (int m=1;m<64;m<<=1){ s1 += __shfl_xor(s1,m,64); s2 += __shfl_xor(s2,m,64); }
  if ((tid & 63) == 0){ red[(tid>>6)*2] = s1; red[(tid>>6)*2+1] = s2; }
  __syncthreads();
  float S1 = red[0]+red[2], S2 = red[1]+red[3];
  float mean = S1/128.f;
  float var  = S2/128.f - mean*mean;
  out[(size_t)bt*128 + tid] = (val-mean)*rsqrtf(var+1e-3f)*g[tid] + be[tid];
}

// ---------------------------------------------------------------- generic LN over 128
__global__ __launch_bounds__(128) void k_ln128(
    const float* __restrict__ in, const float* __restrict__ g,
    const float* __restrict__ be, float* __restrict__ out)
{
  int bt = blockIdx.x, tid = threadIdx.x;
  float x = in[(size_t)bt*128 + tid];
  __shared__ float red[4];
  float s1 = x, s2 = x*x;
#pragma unroll
  for (int m=1;m<64;m<<=1){ s1 += __shfl_xor(s1,m,64); s2 += __shfl_xor(s2,m,64); }
  if ((tid & 63) == 0){ red[(tid>>6)*2] = s1; red[(tid>>6)*2+1] = s2; }
  __syncthreads();
  float S1 = red[0]+red[2], S2 = red[1]+red[3];
  float mean = S1/128.f;
  float var  = S2/128.f - mean*mean;
  out[(size_t)bt*128 + tid] = (x-mean)*rsqrtf(var+1e-3f)*g[tid] + be[tid];
}

// ---------------------------------------------------------------- u_hat precompute (np-major out)
// out layout: [b][np = n*CO+o][T=512][CD] — lanes (consecutive t) write contiguous.
template<int CO, int CD>
__global__ __launch_bounds__(256) void k_uhat(
    const float* __restrict__ src, const float* __restrict__ W,
    const float* __restrict__ Bs, f16* __restrict__ out)
{
  constexpr int NP = 80*CO;
  int wid = __builtin_amdgcn_readfirstlane(blockIdx.x*4 + (threadIdx.x >> 6));
  int lane = threadIdx.x & 63;
  int n   = wid % 80;
  int btc = wid / 80;
  int bt = btc*64 + lane;
  int b = bt >> 9, t = bt & 511;
  int k = n >> 4, i = n & 15;
  int ts = t + k - 2;
  float x[8];
  if (ts >= 0 && ts < 512) {
    const float* xr = src + ((size_t)(b*512+ts)*16 + i)*8;
    f32x4 x0 = *(const f32x4*)xr;
    f32x4 x1 = *(const f32x4*)(xr+4);
#pragma unroll
    for (int q=0;q<4;q++){ x[q]=x0[q]; x[4+q]=x1[q]; }
  } else {
#pragma unroll
    for (int q=0;q<8;q++) x[q]=0.f;
  }
  const float* Wn = W  + (size_t)n*CO*CD*8;
  const float* Bn = Bs + (size_t)n*CO*CD;
  for (int o=0; o<CO; o++) {
    alignas(16) f16 res[CD];
#pragma unroll
    for (int p=0;p<CD;p++) {
      float a = Bn[o*CD+p];
#pragma unroll
      for (int q=0;q<8;q++) a += Wn[(o*CD+p)*8+q]*x[q];
      res[p] = (f16)a;
    }
    f16* op = out + ((size_t)(b*NP + n*CO + o)*512 + t)*CD;
    *(uint4*)op = *(const uint4*)res;
    if constexpr (CD==16) *((uint4*)op+1) = *((const uint4*)res+1);
  }
}

// ---------------------------------------------------------------- routing scan v10 = v8 logic, np-major layout
// uh layout [b][np][T][CD]: per-thread constant uoff = np*T*CD; per-step bump = CD.
template<int CO, int CD, int NW, bool MASK>
__global__ __launch_bounds__(NW*64, 1) void k_scan10(
    const f16* __restrict__ uh, float* __restrict__ vseq, int T)
{
  constexpr int TH = NW*64;
  constexpr int JPW = 64/CO;                 // jj groups per wave (2 or 4)
  constexpr int NJ  = NW*JPW;                // 16 (L1) or 40 (L0)
  constexpr int SLOTS = 80/NJ;               // 5 (L1) or 2 (L0) — exact
  constexpr int NP = 80*CO;
  constexpr int QN = CO*CD;                  // 512 (L1) / 128 (L0)
  constexpr int NV = CD/8;
  constexpr int PSTR = (CD==16) ? 20 : 12;   // part row stride (f32), padded
  constexpr int SSTR = (CD==16) ? 12 : 4;    // smat row stride (u32)

  __shared__ float    part[NW*CO*PSTR];
  __shared__ unsigned smat[CO*SSTR];

  const int b = blockIdx.x;
  const int tid = threadIdx.x;
  const int wv = tid >> 6, lane = tid & 63;
  const int o  = (CO==32) ? ((lane & 15) | (((lane>>5)&1)<<4)) : (lane & 15);
  const int jw = (CO==32) ? ((lane>>4)&1) : (lane>>4);
  const int jj = jw + JPW*wv;

  const f16* __restrict__ ubase = uh + (size_t)b*NP*T*CD;
  float* __restrict__ vb = vseq + (size_t)b*T*QN;

  unsigned uoff[SLOTS];
#pragma unroll
  for (int s=0;s<SLOTS;s++)
    uoff[s] = (unsigned)((jj + NJ*s)*CO + o)*T*CD;

  union VHU { unsigned w[CD/2]; f16x2 h2[CD/2]; uint4 q4[NV]; } vh;
#pragma unroll
  for (int q=0;q<CD/2;q++) vh.w[q] = 0u;

  f16x8 UA[SLOTS][NV], UB[SLOTS][NV];

#define LOADU(U, PTR) do {                                                   \
  _Pragma("unroll") for (int s_=0; s_<SLOTS; ++s_)                           \
  _Pragma("unroll") for (int q_=0; q_<NV; ++q_)                              \
    U[s_][q_] = *(const f16x8*)((PTR) + uoff[s_] + q_*8);                    \
} while(0)

#define STEP(U, TT) do {                                                     \
  float c_[SLOTS];                                                           \
  _Pragma("unroll") for (int s_=0; s_<SLOTS; ++s_) {                         \
    float a_ = 0.f;                                                          \
    _Pragma("unroll") for (int q_=0; q_<NV; ++q_) {                          \
      const f16x2* u2_ = (const f16x2*)&U[s_][q_];                           \
      _Pragma("unroll") for (int z_=0; z_<4; ++z_)                           \
        a_ = __builtin_amdgcn_fdot2(u2_[z_], vh.h2[q_*4+z_], a_, false);     \
    }                                                                        \
    float ex_ = __builtin_amdgcn_exp2f(a_);   /* v stored pre-scaled */      \
    if (MASK && o == 0) ex_ = 0.f;                                           \
    float sm_ = ex_;                                                         \
    sm_ = dpp_add<0x121>(sm_); sm_ = dpp_add<0x122>(sm_);                    \
    sm_ = dpp_add<0x124>(sm_); sm_ = dpp_add<0x128>(sm_);                    \
    if (CO == 32) sm_ = pl32_add(sm_);                                       \
    c_[s_] = ex_ * __builtin_amdgcn_rcpf(sm_);                               \
  }                                                                          \
  /* PV: packed f16 fma, one unpack to f32 afterwards */                     \
  f16x2 pp2_[CD/2];                                                          \
  _Pragma("unroll") for (int r_=0; r_<CD/2; ++r_) pp2_[r_] = (f16x2){0,0};   \
  _Pragma("unroll") for (int s_=0; s_<SLOTS; ++s_) {                         \
    f16 ch_ = (f16)c_[s_];                                                   \
    f16x2 c2_ = { ch_, ch_ };                                                \
    _Pragma("unroll") for (int q_=0; q_<NV; ++q_) {                          \
      const f16x2* u2_ = (const f16x2*)&U[s_][q_];                           \
      _Pragma("unroll") for (int z_=0; z_<4; ++z_)                           \
        pp2_[q_*4+z_] += u2_[z_] * c2_;                                      \
    }                                                                        \
  }                                                                          \
  float pp_[CD];                                                             \
  _Pragma("unroll") for (int r_=0; r_<CD/2; ++r_) {                          \
    pp_[2*r_]   = (float)pp2_[r_][0];                                        \
    pp_[2*r_+1] = (float)pp2_[r_][1];                                        \
  }                                                                          \
  _Pragma("unroll") for (int p_=0; p_<CD; ++p_) {                            \
    pp_[p_] = swap16_add(pp_[p_]);                                           \
    if (CO == 16) pp_[p_] = pl32_add(pp_[p_]);                               \
  }                                                                          \
  if (jw == 0) {                                                             \
    float* pr_ = &part[(wv*CO + o)*PSTR];                                    \
    _Pragma("unroll") for (int p_=0; p_<CD; p_+=4) {                         \
      f32x4 w4_ = { pp_[p_], pp_[p_+1], pp_[p_+2], pp_[p_+3] };              \
      *(f32x4*)(pr_ + p_) = w4_;                                             \
    }                                                                        \
  }                                                                          \
  lds_barrier();                                                             \
  if (QN == TH || tid < QN) {                                                \
    const int p2_ = tid & (CD-1), o2_ = tid >> ((CD==16)?4:3);               \
    float sv_ = 0.f;                                                         \
    _Pragma("unroll") for (int w_=0; w_<NW; ++w_)                            \
      sv_ += part[(w_*CO + o2_)*PSTR + p2_];                                 \
    float sq_ = sv_*sv_;                                                     \
    if (CD == 16) {                                                          \
      sq_ = dpp_add<0x121>(sq_); sq_ = dpp_add<0x122>(sq_);                  \
      sq_ = dpp_add<0x124>(sq_); sq_ = dpp_add<0x128>(sq_);                  \
    } else {                                                                 \
      sq_ = dpp_add<0xB1>(sq_); sq_ = dpp_add<0x4E>(sq_);                    \
      sq_ = dpp_add<0x141>(sq_);                                             \
    }                                                                        \
    float f_ = sq_ * __builtin_amdgcn_rcpf(1.f + sq_) * rsqrtf(sq_ + 1e-9f); \
    float vn_ = sv_ * f_;                                                    \
    vb[(size_t)(TT)*QN + tid] = vn_;                                         \
    float vn1_ = dpp_get<0xB1>(vn_);                                         \
    if ((p2_ & 1) == 0) {                                                    \
      union { f16x2 h2; unsigned w; } pk_;                                   \
      pk_.h2 = (f16x2){ (f16)(vn_*1.44269504f), (f16)(vn1_*1.44269504f) };   \
      smat[o2_*SSTR + (p2_>>1)] = pk_.w;                                     \
    }                                                                        \
  }                                                                          \
  lds_barrier();                                                             \
  _Pragma("unroll") for (int q_=0; q_<NV; ++q_)                              \
    vh.q4[q_] = *(const uint4*)&smat[o*SSTR + q_*4];                         \
} while(0)

  const f16* pcur = ubase;
  for (int t=0; t<T; t+=2) {
    if (t == 0) LOADU(UA, pcur);
    LOADU(UB, pcur + CD);          // tile t+1
    STEP(UA, t);
    LOADU(UA, pcur + 2*CD);        // tile t+2 (tail overread stays in ws)
    STEP(UB, t+1);
    pcur += 2*CD;
  }
#undef LOADU
#undef STEP
}

// ---------------------------------------------------------------- final: LN512 -> length -> LN32
__global__ __launch_bounds__(512) void k_final(
    const float* __restrict__ v1,
    const float* __restrict__ g1, const float* __restrict__ b1,
    const float* __restrict__ g2, const float* __restrict__ b2,
    float* __restrict__ out)
{
  int bt = blockIdx.x;
  int tid = threadIdx.x;
  float x = v1[(size_t)bt*512 + tid];
  __shared__ float red[16];
  __shared__ float Ls[32];
  float s1 = x, s2 = x*x;
#pragma unroll
  for (int m=1;m<64;m<<=1){ s1 += __shfl_xor(s1,m,64); s2 += __shfl_xor(s2,m,64); }
  if ((tid & 63) == 0){ red[(tid>>6)*2] = s1; red[(tid>>6)*2+1] = s2; }
  __syncthreads();
  float S1 = 0.f, S2 = 0.f;
#pragma unroll
  for (int i=0;i<8;i++){ S1 += red[2*i]; S2 += red[2*i+1]; }
  float mean = S1/512.f, var = S2/512.f - mean*mean;
  float y = (x-mean)*rsqrtf(var+1e-3f)*g1[tid] + b1[tid];
  float ss = y*y;
  ss += __shfl_xor(ss,1,16); ss += __shfl_xor(ss,2,16);
  ss += __shfl_xor(ss,4,16); ss += __shfl_xor(ss,8,16);
  float L = sqrtf(ss + 1e-9f);
  if ((tid & 15) == 0) Ls[tid >> 4] = L;
  __syncthreads();
  if (tid < 32) {
    float l = Ls[tid];
    float t1 = l, t2 = l*l;
#pragma unroll
    for (int m=1;m<32;m<<=1){ t1 += __shfl_xor(t1,m,32); t2 += __shfl_xor(t2,m,32); }
    float mn = t1/32.f, vr = t2/32.f - mn*mn;
    out[(size_t)bt*32 + tid] = (l-mn)*rsqrtf(vr+1e-3f)*g2[tid] + b2[tid];
  }
}

// ---------------------------------------------------------------- workspace layout
static const size_t OFF_X1F   = 0;            // 20,971,520 B f16 [4,1024,40,64]
static const size_t OFF_WT16  = 20971520;     //     77,824 B f16 [64][600]
static const size_t OFF_PWT   = 21049344;     //     40,960 B f16 [16][1280]
static const size_t OFF_X2F   = 21090304;     //  5,242,880 B f16 [2048][1280]
static const size_t OFF_EMB0  = 26333184;     //    131,072 B f32 [2048][16]
static const size_t OFF_UH0   = 26464256;     // 41,943,040 B f16 [4][1280][512][8]
static const size_t OFF_UH1   = 0;            // 167,772,160 B f16 [4][2560][512][16] (reuses dead frontend)
static const size_t OFF_EMBLN = 167772160;    //  1,048,576 B f32 (dead before scan0)
static const size_t OFF_V0    = 167772160;    //  1,048,576 B f32 (reuses EMBLN slot)
static const size_t OFF_V0LN  = 168820736;    //  1,048,576 B f32
static const size_t OFF_V1    = 169869312;    //  4,194,304 B f32 [4,512,32,16]
static const size_t WS_NEED   = 174063616;

extern "C" void kernel_launch(void* const* d_in, const int* in_sizes, int n_in,
                              void* d_out, int out_size, void* d_ws, size_t ws_size,
                              hipStream_t stream) {
  (void)in_sizes; (void)n_in; (void)out_size;
  if (ws_size < WS_NEED) return;

  const float* inputs = (const float*)d_in[0];
  const int*   lens   = (const int*)d_in[1];
  const float* c1w=(const float*)d_in[2],  *c1b=(const float*)d_in[3];
  const float* c2w=(const float*)d_in[4],  *c2b=(const float*)d_in[5];
  const float* pw =(const float*)d_in[6],  *pb =(const float*)d_in[7];
  const float* e0w=(const float*)d_in[8],  *e0b=(const float*)d_in[9];
  const float* e1w=(const float*)d_in[10], *e1b=(const float*)d_in[11];
  const float* lnig=(const float*)d_in[12],*lnib=(const float*)d_in[13];
  const float* W0=(const float*)d_in[14],  *B0=(const float*)d_in[15];
  const float* W1=(const float*)d_in[16],  *B1=(const float*)d_in[17];
  const float* lnm0g=(const float*)d_in[18],*lnm0b=(const float*)d_in[19];
  const float* lnm1g=(const float*)d_in[20],*lnm1b=(const float*)d_in[21];
  const float* lnog=(const float*)d_in[22], *lnob=(const float*)d_in[23];

  char* ws = (char*)d_ws;
  f16*   x1f   = (f16*)  (ws + OFF_X1F);
  f16*   wt16  = (f16*)  (ws + OFF_WT16);
  f16*   pwT   = (f16*)  (ws + OFF_PWT);
  f16*   x2f   = (f16*)  (ws + OFF_X2F);
  float* emb0  = (float*)(ws + OFF_EMB0);
  f16*   uh0   = (f16*)  (ws + OFF_UH0);
  f16*   uh1   = (f16*)  (ws + OFF_UH1);
  float* embln = (float*)(ws + OFF_EMBLN);
  float* v0    = (float*)(ws + OFF_V0);
  float* v0ln  = (float*)(ws + OFF_V0LN);
  float* v1    = (float*)(ws + OFF_V1);

  k_conv1<<<40960, 256, 0, stream>>>(inputs, c1w, c1b, x1f);
  k_wcvt <<<152, 256, 0, stream>>>(c2w, wt16);
  k_wcvtp<<<80, 256, 0, stream>>>(pw, pwT);
  k_conv2m<<<320, 256, 0, stream>>>(x1f, wt16, c2b, x2f);
  k_projm<<<32, 256, 0, stream>>>(x2f, pwT, pb, emb0);
  k_primary<<<2048, 128, 0, stream>>>(emb0, e0w, e0b, e1w, e1b, lnig, lnib, lens, embln);
  k_uhat<16,8><<<640, 256, 0, stream>>>(embln, W0, B0, uh0);
  k_scan10<16,8,10,false><<<4, 640, 0, stream>>>(uh0, v0, 512);
  k_ln128<<<2048, 128, 0, stream>>>(v0, lnm0g, lnm0b, v0ln);
  k_uhat<32,16><<<640, 256, 0, stream>>>(v0ln, W1, B1, uh1);
  k_scan10<32,16,8,true><<<4, 512, 0, stream>>>(uh1, v1, 512);
  k_final<<<2048, 512, 0, stream>>>(v1, lnm1g, lnm1b, lnog, lnob, (float*)d_out);
}

// Round 12
// 1744.573 us; speedup vs baseline: 1.3361x; 1.2518x over previous
//
#include <hip/hip_runtime.h>
#include <hip/hip_fp16.h>

typedef _Float16 f16;
typedef _Float16 f16x2 __attribute__((ext_vector_type(2)));
typedef _Float16 f16x8 __attribute__((ext_vector_type(8)));
typedef float f32x4 __attribute__((ext_vector_type(4)));

#define DEV static __device__ __forceinline__

// LDS-only barrier — keeps global loads/stores in flight.
DEV void lds_barrier() {
  asm volatile("s_waitcnt lgkmcnt(0)" ::: "memory");
  __builtin_amdgcn_s_barrier();
  asm volatile("" ::: "memory");
}

// ---- VALU cross-lane reduction helpers (no DS pipe) ----
template<int CTRL>
DEV float dpp_add(float x) {
  int y = __builtin_amdgcn_update_dpp(0, __builtin_bit_cast(int, x), CTRL, 0xf, 0xf, false);
  return x + __builtin_bit_cast(float, y);
}
template<int CTRL>
DEV float dpp_get(float x) {
  int y = __builtin_amdgcn_update_dpp(0, __builtin_bit_cast(int, x), CTRL, 0xf, 0xf, false);
  return __builtin_bit_cast(float, y);
}
DEV float pl32_add(float x) {  // x + x[lane^32]
  unsigned xi = __builtin_bit_cast(unsigned, x);
  auto r = __builtin_amdgcn_permlane32_swap(xi, xi, false, false);
  return __builtin_bit_cast(float, (unsigned)r[0]) + __builtin_bit_cast(float, (unsigned)r[1]);
}
DEV float swap16_add(float x) {  // x + x[lane^16]
#if __has_builtin(__builtin_amdgcn_permlane16_swap)
  unsigned xi = __builtin_bit_cast(unsigned, x);
  auto r = __builtin_amdgcn_permlane16_swap(xi, xi, false, false);
  return __builtin_bit_cast(float, (unsigned)r[0]) + __builtin_bit_cast(float, (unsigned)r[1]);
#else
  int y = __builtin_amdgcn_ds_swizzle(__builtin_bit_cast(int, x), 0x401F);
  return x + __builtin_bit_cast(float, y);
#endif
}

// ---------------------------------------------------------------- conv1
__global__ __launch_bounds__(256) void k_conv1(
    const float* __restrict__ in, const float* __restrict__ w,
    const float* __restrict__ bias, f16* __restrict__ out)
{
  int idx = blockIdx.x*256 + threadIdx.x;
  int co = idx & 63;
  int ow = (idx >> 6) % 40;
  int oh = ((idx >> 6) / 40) % 1024;
  int b  = idx / (64*40*1024);
  float acc = bias[co];
#pragma unroll
  for (int kh=0; kh<3; kh++) {
    int ih = oh*2 + kh;
    if (ih >= 2048) continue;
#pragma unroll
    for (int kw=0; kw<3; kw++) {
      int iw = ow*2 + kw;
      if (iw >= 80) continue;
      acc += in[(b*2048 + ih)*80 + iw] * w[(kh*3+kw)*64 + co];
    }
  }
  out[idx] = (f16)fmaxf(acc, 0.f);
}

// ---------------------------------------------------------------- weight convert+transpose (conv2)
__global__ __launch_bounds__(256) void k_wcvt(
    const float* __restrict__ w, f16* __restrict__ wt)
{
  int idx = blockIdx.x*256 + threadIdx.x;
  if (idx >= 38912) return;
  f16 v = (f16)0.f;
  if (idx < 38400) {
    int n = idx / 600, k = idx % 600;
    if (k < 576) v = (f16)w[k*64 + n];
  }
  wt[idx] = v;
}

// ---------------------------------------------------------------- proj weight transpose: pw [1280][16] -> pwT f16 [16][1280]
__global__ __launch_bounds__(256) void k_wcvtp(
    const float* __restrict__ pw, f16* __restrict__ pwT)
{
  int idx = blockIdx.x*256 + threadIdx.x;
  if (idx >= 20480) return;
  int j = idx / 1280, f = idx % 1280;
  pwT[idx] = (f16)pw[f*16 + j];
}

// ---------------------------------------------------------------- conv2 as implicit GEMM (MFMA fp16) -> f16 out
__global__ __launch_bounds__(256) void k_conv2m(
    const f16* __restrict__ x1f, const f16* __restrict__ wt,
    const float* __restrict__ bias, f16* __restrict__ out)
{
  __shared__ f16 Bt[38912];
  const int tid = threadIdx.x;
  for (int it = 0; it < 19; ++it) {
    const f16* g = wt + it*2048 + tid*8;
    f16* l = Bt + it*2048 + tid*8;
    __builtin_amdgcn_global_load_lds(
        (const __attribute__((address_space(1))) void*)g,
        (__attribute__((address_space(3))) void*)l, 16, 0, 0);
  }
  __syncthreads();

  const int wave = tid >> 6, l = tid & 63;
  const int lrow = l & 15, lk = l >> 4;
  const int m0 = blockIdx.x*128 + wave*32;

  const int mA = m0 + lrow, mB = m0 + 16 + lrow;
  int bA = mA/10240, rA = mA%10240, ohA = rA/20, owA = rA%20;
  int bB = mB/10240, rB = mB%10240, ohB = rB/20, owB = rB%20;
  const f16* pA = x1f + ((size_t)((bA*1024 + ohA*2)*40 + owA*2))*64;
  const f16* pB = x1f + ((size_t)((bB*1024 + ohB*2)*40 + owB*2))*64;

  f32x4 acc[2][4];
#pragma unroll
  for (int i=0;i<2;i++)
#pragma unroll
    for (int j=0;j<4;j++) acc[i][j] = (f32x4){0.f,0.f,0.f,0.f};

  const f16x8 zero8 = {};
#pragma unroll
  for (int kk=0; kk<18; ++kk) {
    const int tap = kk >> 1;
    const int kh = tap/3, kw = tap%3;
    const int ci0 = ((kk&1)<<5) + lk*8;
    const int off = (kh*40 + kw)*64 + ci0;
    const bool okA = (ohA*2+kh < 1024) && (owA*2+kw < 40);
    const bool okB = (ohB*2+kh < 1024) && (owB*2+kw < 40);
    f16x8 a0 = okA ? *(const f16x8*)(pA + off) : zero8;
    f16x8 a1 = okB ? *(const f16x8*)(pB + off) : zero8;
#pragma unroll
    for (int nf=0; nf<4; ++nf) {
      f16x8 bb = *(const f16x8*)&Bt[(nf*16 + lrow)*600 + kk*32 + lk*8];
      acc[0][nf] = __builtin_amdgcn_mfma_f32_16x16x32_f16(a0, bb, acc[0][nf], 0,0,0);
      acc[1][nf] = __builtin_amdgcn_mfma_f32_16x16x32_f16(a1, bb, acc[1][nf], 0,0,0);
    }
  }
#pragma unroll
  for (int nf=0; nf<4; ++nf) {
    const int n = nf*16 + lrow;
    const float bi = bias[n];
#pragma unroll
    for (int mf=0; mf<2; ++mf)
#pragma unroll
      for (int r=0; r<4; ++r) {
        int mrow = m0 + mf*16 + lk*4 + r;
        out[(size_t)mrow*64 + n] = (f16)fmaxf(acc[mf][nf][r] + bi, 0.f);
      }
  }
}

// ---------------------------------------------------------------- proj as MFMA GEMM
// x2f f16 [2048][1280] @ pwT f16 [16][1280] -> emb0 f32 [2048][16]
__global__ __launch_bounds__(256) void k_projm(
    const f16* __restrict__ x2f, const f16* __restrict__ pwT,
    const float* __restrict__ pb, float* __restrict__ out)
{
  const int tid = threadIdx.x;
  const int wave = tid >> 6, l = tid & 63;
  const int lrow = l & 15, lk = l >> 4;
  const int m0 = (blockIdx.x*4 + wave)*16;
  const f16* pA = x2f + (size_t)(m0 + lrow)*1280 + lk*8;
  const f16* pB = pwT + (size_t)lrow*1280 + lk*8;
  f32x4 acc = {0.f,0.f,0.f,0.f};
#pragma unroll 4
  for (int k=0; k<40; ++k) {
    f16x8 a  = *(const f16x8*)(pA + k*32);
    f16x8 bb = *(const f16x8*)(pB + k*32);
    acc = __builtin_amdgcn_mfma_f32_16x16x32_f16(a, bb, acc, 0,0,0);
  }
#pragma unroll
  for (int r=0; r<4; ++r) {
    int row = m0 + lk*4 + r;
    out[(size_t)row*16 + lrow] = acc[r] + pb[lrow];
  }
}

// ------------------------------------------- primary caps
__global__ __launch_bounds__(128) void k_primary(
    const float* __restrict__ emb0,
    const float* __restrict__ w0, const float* __restrict__ b0,
    const float* __restrict__ w1, const float* __restrict__ b1,
    const float* __restrict__ g, const float* __restrict__ be,
    const int* __restrict__ lens, float* __restrict__ out)
{
  int bt = blockIdx.x;
  int b = bt >> 9, t = bt & 511;
  int tid = threadIdx.x;
  int c = tid & 7, j = tid >> 3;
  __shared__ float rows[3][16];
  __shared__ float red[4];
  if (tid < 48) {
    int kh = tid / 16, jj = tid % 16;
    int ts = t + kh - 1;
    rows[kh][jj] = (ts >= 0 && ts < 512) ? emb0[(b*512+ts)*16 + jj] : 0.f;
  }
  __syncthreads();
  float a0 = b0[c], a1 = b1[c];
#pragma unroll
  for (int kh=0; kh<3; kh++)
#pragma unroll
    for (int kw=0; kw<3; kw++) {
      int jj = j + kw - 1;
      if (jj < 0 || jj >= 16) continue;
      float xv = rows[kh][jj];
      a0 += xv * w0[(kh*3+kw)*8 + c];
      a1 += xv * w1[(kh*3+kw)*8 + c];
    }
  float e = fmaxf(a0, a1);
  int valid = (lens[b] + 3) >> 2;
  if (t >= valid) e = 0.f;
  float sq = e*e;
  sq += __shfl_xor(sq, 1, 8); sq += __shfl_xor(sq, 2, 8); sq += __shfl_xor(sq, 4, 8);
  float val = e * (sq / (1.f + sq)) * rsqrtf(sq + 1e-9f);
  float s1 = val, s2 = val*val;
#pragma unroll
  for (int m=1;m<64;m<<=1){ s1 += __shfl_xor(s1,m,64); s2 += __shfl_xor(s2,m,64); }
  if ((tid & 63) == 0){ red[(tid>>6)*2] = s1; red[(tid>>6)*2+1] = s2; }
  __syncthreads();
  float S1 = red[0]+red[2], S2 = red[1]+red[3];
  float mean = S1/128.f;
  float var  = S2/128.f - mean*mean;
  out[(size_t)bt*128 + tid] = (val-mean)*rsqrtf(var+1e-3f)*g[tid] + be[tid];
}

// ---------------------------------------------------------------- generic LN over 128
__global__ __launch_bounds__(128) void k_ln128(
    const float* __restrict__ in, const float* __restrict__ g,
    const float* __restrict__ be, float* __restrict__ out)
{
  int bt = blockIdx.x, tid = threadIdx.x;
  float x = in[(size_t)bt*128 + tid];
  __shared__ float red[4];
  float s1 = x, s2 = x*x;
#pragma unroll
  for (int m=1;m<64;m<<=1){ s1 += __shfl_xor(s1,m,64); s2 += __shfl_xor(s2,m,64); }
  if ((tid & 63) == 0){ red[(tid>>6)*2] = s1; red[(tid>>6)*2+1] = s2; }
  __syncthreads();
  float S1 = red[0]+red[2], S2 = red[1]+red[3];
  float mean = S1/128.f;
  float var  = S2/128.f - mean*mean;
  out[(size_t)bt*128 + tid] = (x-mean)*rsqrtf(var+1e-3f)*g[tid] + be[tid];
}

// ---------------------------------------------------------------- u_hat precompute (t-major, coalesced for scan)
template<int CO, int CD>
__global__ __launch_bounds__(256) void k_uhat(
    const float* __restrict__ src, const float* __restrict__ W,
    const float* __restrict__ Bs, f16* __restrict__ out)
{
  constexpr int NP = 80*CO;
  int wid = __builtin_amdgcn_readfirstlane(blockIdx.x*4 + (threadIdx.x >> 6));
  int lane = threadIdx.x & 63;
  int n   = wid % 80;
  int btc = wid / 80;
  int bt = btc*64 + lane;
  int b = bt >> 9, t = bt & 511;
  int k = n >> 4, i = n & 15;
  int ts = t + k - 2;
  float x[8];
  if (ts >= 0 && ts < 512) {
    const float* xr = src + ((size_t)(b*512+ts)*16 + i)*8;
    f32x4 x0 = *(const f32x4*)xr;
    f32x4 x1 = *(const f32x4*)(xr+4);
#pragma unroll
    for (int q=0;q<4;q++){ x[q]=x0[q]; x[4+q]=x1[q]; }
  } else {
#pragma unroll
    for (int q=0;q<8;q++) x[q]=0.f;
  }
  const float* Wn = W  + (size_t)n*CO*CD*8;
  const float* Bn = Bs + (size_t)n*CO*CD;
  for (int o=0; o<CO; o++) {
    alignas(16) f16 res[CD];
#pragma unroll
    for (int p=0;p<CD;p++) {
      float a = Bn[o*CD+p];
#pragma unroll
      for (int q=0;q<8;q++) a += Wn[(o*CD+p)*8+q]*x[q];
      res[p] = (f16)a;
    }
    f16* op = out + ((size_t)bt*NP + (size_t)n*CO + o)*CD;
    *(uint4*)op = *(const uint4*)res;
    if constexpr (CD==16) *((uint4*)op+1) = *((const uint4*)res+1);
  }
}

// ---------------------------------------------------------------- routing scan v8 (known-good 707 µs config)
// t-major uh [b][T][np][CD]; per-wave loads span contiguous ~2KB (good coalescing).
// pk_fma PV, exp2 softmax with pre-scaled v, DPP/permlane reductions, padded LDS.
template<int CO, int CD, int NW, bool MASK>
__global__ __launch_bounds__(NW*64, 1) void k_scan8(
    const f16* __restrict__ uh, float* __restrict__ vseq, int T)
{
  constexpr int TH = NW*64;
  constexpr int JPW = 64/CO;                 // jj groups per wave (2 or 4)
  constexpr int NJ  = NW*JPW;                // 16 (L1) or 40 (L0)
  constexpr int SLOTS = 80/NJ;               // 5 (L1) or 2 (L0) — exact
  constexpr int NP = 80*CO;
  constexpr int QN = CO*CD;                  // 512 (L1) / 128 (L0)
  constexpr int NV = CD/8;
  constexpr int PSTR = (CD==16) ? 20 : 12;   // part row stride (f32), padded
  constexpr int SSTR = (CD==16) ? 12 : 4;    // smat row stride (u32)

  __shared__ float    part[NW*CO*PSTR];
  __shared__ unsigned smat[CO*SSTR];

  const int b = blockIdx.x;
  const int tid = threadIdx.x;
  const int wv = tid >> 6, lane = tid & 63;
  const int o  = (CO==32) ? ((lane & 15) | (((lane>>5)&1)<<4)) : (lane & 15);
  const int jw = (CO==32) ? ((lane>>4)&1) : (lane>>4);
  const int jj = jw + JPW*wv;

  const f16* __restrict__ ubase = uh + (size_t)b*T*NP*CD;
  float* __restrict__ vb = vseq + (size_t)b*T*QN;

  unsigned uoff[SLOTS];
#pragma unroll
  for (int s=0;s<SLOTS;s++)
    uoff[s] = (unsigned)((jj + NJ*s)*CO + o)*CD;

  union VHU { unsigned w[CD/2]; f16x2 h2[CD/2]; uint4 q4[NV]; } vh;
#pragma unroll
  for (int q=0;q<CD/2;q++) vh.w[q] = 0u;

  f16x8 UA[SLOTS][NV], UB[SLOTS][NV];

#define LOADU(U, PTR) do {                                                   \
  _Pragma("unroll") for (int s_=0; s_<SLOTS; ++s_)                           \
  _Pragma("unroll") for (int q_=0; q_<NV; ++q_)                              \
    U[s_][q_] = *(const f16x8*)((PTR) + uoff[s_] + q_*8);                    \
} while(0)

#define STEP(U, TT) do {                                                     \
  float c_[SLOTS];                                                           \
  _Pragma("unroll") for (int s_=0; s_<SLOTS; ++s_) {                         \
    float a_ = 0.f;                                                          \
    _Pragma("unroll") for (int q_=0; q_<NV; ++q_) {                          \
      const f16x2* u2_ = (const f16x2*)&U[s_][q_];                           \
      _Pragma("unroll") for (int z_=0; z_<4; ++z_)                           \
        a_ = __builtin_amdgcn_fdot2(u2_[z_], vh.h2[q_*4+z_], a_, false);     \
    }                                                                        \
    float ex_ = __builtin_amdgcn_exp2f(a_);   /* v stored pre-scaled */      \
    if (MASK && o == 0) ex_ = 0.f;                                           \
    float sm_ = ex_;                                                         \
    sm_ = dpp_add<0x121>(sm_); sm_ = dpp_add<0x122>(sm_);                    \
    sm_ = dpp_add<0x124>(sm_); sm_ = dpp_add<0x128>(sm_);                    \
    if (CO == 32) sm_ = pl32_add(sm_);                                       \
    c_[s_] = ex_ * __builtin_amdgcn_rcpf(sm_);                               \
  }                                                                          \
  /* PV: packed f16 fma (v_pk_fma_f16), one unpack to f32 afterwards */      \
  f16x2 pp2_[CD/2];                                                          \
  _Pragma("unroll") for (int r_=0; r_<CD/2; ++r_) pp2_[r_] = (f16x2){0,0};   \
  _Pragma("unroll") for (int s_=0; s_<SLOTS; ++s_) {                         \
    f16 ch_ = (f16)c_[s_];                                                   \
    f16x2 c2_ = { ch_, ch_ };                                                \
    _Pragma("unroll") for (int q_=0; q_<NV; ++q_) {                          \
      const f16x2* u2_ = (const f16x2*)&U[s_][q_];                           \
      _Pragma("unroll") for (int z_=0; z_<4; ++z_)                           \
        pp2_[q_*4+z_] += u2_[z_] * c2_;                                      \
    }                                                                        \
  }                                                                          \
  float pp_[CD];                                                             \
  _Pragma("unroll") for (int r_=0; r_<CD/2; ++r_) {                          \
    pp_[2*r_]   = (float)pp2_[r_][0];                                        \
    pp_[2*r_+1] = (float)pp2_[r_][1];                                        \
  }                                                                          \
  _Pragma("unroll") for (int p_=0; p_<CD; ++p_) {                            \
    pp_[p_] = swap16_add(pp_[p_]);                                           \
    if (CO == 16) pp_[p_] = pl32_add(pp_[p_]);                               \
  }                                                                          \
  if (jw == 0) {                                                             \
    float* pr_ = &part[(wv*CO + o)*PSTR];                                    \
    _Pragma("unroll") for (int p_=0; p_<CD; p_+=4) {                         \
      f32x4 w4_ = { pp_[p_], pp_[p_+1], pp_[p_+2], pp_[p_+3] };              \
      *(f32x4*)(pr_ + p_) = w4_;                                             \
    }                                                                        \
  }                                                                          \
  lds_barrier();                                                             \
  if (QN == TH || tid < QN) {                                                \
    const int p2_ = tid & (CD-1), o2_ = tid >> ((CD==16)?4:3);               \
    float sv_ = 0.f;                                                         \
    _Pragma("unroll") for (int w_=0; w_<NW; ++w_)                            \
      sv_ += part[(w_*CO + o2_)*PSTR + p2_];                                 \
    float sq_ = sv_*sv_;                                                     \
    if (CD == 16) {                                                          \
      sq_ = dpp_add<0x121>(sq_); sq_ = dpp_add<0x122>(sq_);                  \
      sq_ = dpp_add<0x124>(sq_); sq_ = dpp_add<0x128>(sq_);                  \
    } else {                                                                 \
      sq_ = dpp_add<0xB1>(sq_); sq_ = dpp_add<0x4E>(sq_);                    \
      sq_ = dpp_add<0x141>(sq_);                                             \
    }                                                                        \
    float f_ = sq_ * __builtin_amdgcn_rcpf(1.f + sq_) * rsqrtf(sq_ + 1e-9f); \
    float vn_ = sv_ * f_;                                                    \
    vb[(size_t)(TT)*QN + tid] = vn_;                                         \
    float vn1_ = dpp_get<0xB1>(vn_);                                         \
    if ((p2_ & 1) == 0) {                                                    \
      union { f16x2 h2; unsigned w; } pk_;                                   \
      pk_.h2 = (f16x2){ (f16)(vn_*1.44269504f), (f16)(vn1_*1.44269504f) };   \
      smat[o2_*SSTR + (p2_>>1)] = pk_.w;                                     \
    }                                                                        \
  }                                                                          \
  lds_barrier();                                                             \
  _Pragma("unroll") for (int q_=0; q_<NV; ++q_)                              \
    vh.q4[q_] = *(const uint4*)&smat[o*SSTR + q_*4];                         \
} while(0)

  const size_t ST = (size_t)NP*CD;
  const f16* pcur = ubase;
  LOADU(UA, pcur);
  for (int t=0; t<T; t+=2) {
    LOADU(UB, pcur + ST);          // tile t+1
    STEP(UA, t);
    LOADU(UA, pcur + 2*ST);        // tile t+2 (tail overread stays in ws)
    STEP(UB, t+1);
    pcur += 2*ST;
  }
#undef LOADU
#undef STEP
}

// ---------------------------------------------------------------- final: LN512 -> length -> LN32
__global__ __launch_bounds__(512) void k_final(
    const float* __restrict__ v1,
    const float* __restrict__ g1, const float* __restrict__ b1,
    const float* __restrict__ g2, const float* __restrict__ b2,
    float* __restrict__ out)
{
  int bt = blockIdx.x;
  int tid = threadIdx.x;
  float x = v1[(size_t)bt*512 + tid];
  __shared__ float red[16];
  __shared__ float Ls[32];
  float s1 = x, s2 = x*x;
#pragma unroll
  for (int m=1;m<64;m<<=1){ s1 += __shfl_xor(s1,m,64); s2 += __shfl_xor(s2,m,64); }
  if ((tid & 63) == 0){ red[(tid>>6)*2] = s1; red[(tid>>6)*2+1] = s2; }
  __syncthreads();
  float S1 = 0.f, S2 = 0.f;
#pragma unroll
  for (int i=0;i<8;i++){ S1 += red[2*i]; S2 += red[2*i+1]; }
  float mean = S1/512.f, var = S2/512.f - mean*mean;
  float y = (x-mean)*rsqrtf(var+1e-3f)*g1[tid] + b1[tid];
  float ss = y*y;
  ss += __shfl_xor(ss,1,16); ss += __shfl_xor(ss,2,16);
  ss += __shfl_xor(ss,4,16); ss += __shfl_xor(ss,8,16);
  float L = sqrtf(ss + 1e-9f);
  if ((tid & 15) == 0) Ls[tid >> 4] = L;
  __syncthreads();
  if (tid < 32) {
    float l = Ls[tid];
    float t1 = l, t2 = l*l;
#pragma unroll
    for (int m=1;m<32;m<<=1){ t1 += __shfl_xor(t1,m,32); t2 += __shfl_xor(t2,m,32); }
    float mn = t1/32.f, vr = t2/32.f - mn*mn;
    out[(size_t)bt*32 + tid] = (l-mn)*rsqrtf(vr+1e-3f)*g2[tid] + b2[tid];
  }
}

// ---------------------------------------------------------------- workspace layout
static const size_t OFF_X1F   = 0;            // 20,971,520 B f16 [4,1024,40,64]
static const size_t OFF_WT16  = 20971520;     //     77,824 B f16 [64][600]
static const size_t OFF_PWT   = 21049344;     //     40,960 B f16 [16][1280]
static const size_t OFF_X2F   = 21090304;     //  5,242,880 B f16 [2048][1280]
static const size_t OFF_EMB0  = 26333184;     //    131,072 B f32 [2048][16]
static const size_t OFF_UH0   = 26464256;     // 41,943,040 B f16 [4,512,1280,8]
static const size_t OFF_UH1   = 0;            // 167,772,160 B f16 [4,512,2560,16] (reuses dead frontend)
static const size_t OFF_EMBLN = 167772160;    //  1,048,576 B f32 (dead before scan0)
static const size_t OFF_V0    = 167772160;    //  1,048,576 B f32 (reuses EMBLN slot)
static const size_t OFF_V0LN  = 168820736;    //  1,048,576 B f32
static const size_t OFF_V1    = 169869312;    //  4,194,304 B f32 [4,512,32,16]
static const size_t WS_NEED   = 174063616;

extern "C" void kernel_launch(void* const* d_in, const int* in_sizes, int n_in,
                              void* d_out, int out_size, void* d_ws, size_t ws_size,
                              hipStream_t stream) {
  (void)in_sizes; (void)n_in; (void)out_size;
  if (ws_size < WS_NEED) return;

  const float* inputs = (const float*)d_in[0];
  const int*   lens   = (const int*)d_in[1];
  const float* c1w=(const float*)d_in[2],  *c1b=(const float*)d_in[3];
  const float* c2w=(const float*)d_in[4],  *c2b=(const float*)d_in[5];
  const float* pw =(const float*)d_in[6],  *pb =(const float*)d_in[7];
  const float* e0w=(const float*)d_in[8],  *e0b=(const float*)d_in[9];
  const float* e1w=(const float*)d_in[10], *e1b=(const float*)d_in[11];
  const float* lnig=(const float*)d_in[12],*lnib=(const float*)d_in[13];
  const float* W0=(const float*)d_in[14],  *B0=(const float*)d_in[15];
  const float* W1=(const float*)d_in[16],  *B1=(const float*)d_in[17];
  const float* lnm0g=(const float*)d_in[18],*lnm0b=(const float*)d_in[19];
  const float* lnm1g=(const float*)d_in[20],*lnm1b=(const float*)d_in[21];
  const float* lnog=(const float*)d_in[22], *lnob=(const float*)d_in[23];

  char* ws = (char*)d_ws;
  f16*   x1f   = (f16*)  (ws + OFF_X1F);
  f16*   wt16  = (f16*)  (ws + OFF_WT16);
  f16*   pwT   = (f16*)  (ws + OFF_PWT);
  f16*   x2f   = (f16*)  (ws + OFF_X2F);
  float* emb0  = (float*)(ws + OFF_EMB0);
  f16*   uh0   = (f16*)  (ws + OFF_UH0);
  f16*   uh1   = (f16*)  (ws + OFF_UH1);
  float* embln = (float*)(ws + OFF_EMBLN);
  float* v0    = (float*)(ws + OFF_V0);
  float* v0ln  = (float*)(ws + OFF_V0LN);
  float* v1    = (float*)(ws + OFF_V1);

  k_conv1<<<40960, 256, 0, stream>>>(inputs, c1w, c1b, x1f);
  k_wcvt <<<152, 256, 0, stream>>>(c2w, wt16);
  k_wcvtp<<<80, 256, 0, stream>>>(pw, pwT);
  k_conv2m<<<320, 256, 0, stream>>>(x1f, wt16, c2b, x2f);
  k_projm<<<32, 256, 0, stream>>>(x2f, pwT, pb, emb0);
  k_primary<<<2048, 128, 0, stream>>>(emb0, e0w, e0b, e1w, e1b, lnig, lnib, lens, embln);
  k_uhat<16,8><<<640, 256, 0, stream>>>(embln, W0, B0, uh0);
  k_scan8<16,8,10,false><<<4, 640, 0, stream>>>(uh0, v0, 512);
  k_ln128<<<2048, 128, 0, stream>>>(v0, lnm0g, lnm0b, v0ln);
  k_uhat<32,16><<<640, 256, 0, stream>>>(v0ln, W1, B1, uh1);
  k_scan8<32,16,8,true><<<4, 512, 0, stream>>>(uh1, v1, 512);
  k_final<<<2048, 512, 0, stream>>>(v1, lnm1g, lnm1b, lnog, lnob, (float*)d_out);
}

// Round 13
// 1306.978 us; speedup vs baseline: 1.7834x; 1.3348x over previous
//
#include <hip/hip_runtime.h>
#include <hip/hip_fp16.h>

typedef _Float16 f16;
typedef _Float16 f16x2 __attribute__((ext_vector_type(2)));
typedef _Float16 f16x8 __attribute__((ext_vector_type(8)));
typedef float f32x4 __attribute__((ext_vector_type(4)));

#define DEV static __device__ __forceinline__

// LDS-only barrier — keeps global loads/stores in flight.
DEV void lds_barrier() {
  asm volatile("s_waitcnt lgkmcnt(0)" ::: "memory");
  __builtin_amdgcn_s_barrier();
  asm volatile("" ::: "memory");
}

// ---- VALU cross-lane reduction helpers (no DS pipe) ----
template<int CTRL>
DEV float dpp_add(float x) {
  int y = __builtin_amdgcn_update_dpp(0, __builtin_bit_cast(int, x), CTRL, 0xf, 0xf, false);
  return x + __builtin_bit_cast(float, y);
}
template<int CTRL>
DEV float dpp_get(float x) {
  int y = __builtin_amdgcn_update_dpp(0, __builtin_bit_cast(int, x), CTRL, 0xf, 0xf, false);
  return __builtin_bit_cast(float, y);
}
DEV float pl32_add(float x) {  // x + x[lane^32]
  unsigned xi = __builtin_bit_cast(unsigned, x);
  auto r = __builtin_amdgcn_permlane32_swap(xi, xi, false, false);
  return __builtin_bit_cast(float, (unsigned)r[0]) + __builtin_bit_cast(float, (unsigned)r[1]);
}
DEV float swap16_add(float x) {  // x + x[lane^16]
#if __has_builtin(__builtin_amdgcn_permlane16_swap)
  unsigned xi = __builtin_bit_cast(unsigned, x);
  auto r = __builtin_amdgcn_permlane16_swap(xi, xi, false, false);
  return __builtin_bit_cast(float, (unsigned)r[0]) + __builtin_bit_cast(float, (unsigned)r[1]);
#else
  int y = __builtin_amdgcn_ds_swizzle(__builtin_bit_cast(int, x), 0x401F);
  return x + __builtin_bit_cast(float, y);
#endif
}

// ---------------------------------------------------------------- conv1
__global__ __launch_bounds__(256) void k_conv1(
    const float* __restrict__ in, const float* __restrict__ w,
    const float* __restrict__ bias, f16* __restrict__ out)
{
  int idx = blockIdx.x*256 + threadIdx.x;
  int co = idx & 63;
  int ow = (idx >> 6) % 40;
  int oh = ((idx >> 6) / 40) % 1024;
  int b  = idx / (64*40*1024);
  float acc = bias[co];
#pragma unroll
  for (int kh=0; kh<3; kh++) {
    int ih = oh*2 + kh;
    if (ih >= 2048) continue;
#pragma unroll
    for (int kw=0; kw<3; kw++) {
      int iw = ow*2 + kw;
      if (iw >= 80) continue;
      acc += in[(b*2048 + ih)*80 + iw] * w[(kh*3+kw)*64 + co];
    }
  }
  out[idx] = (f16)fmaxf(acc, 0.f);
}

// ---------------------------------------------------------------- merged weight converts
// conv2 w [576][64] -> wt f16 [64][600]; proj pw [1280][16] -> pwT f16 [16][1280]
__global__ __launch_bounds__(256) void k_wcvt2(
    const float* __restrict__ w, const float* __restrict__ pw,
    f16* __restrict__ wt, f16* __restrict__ pwT)
{
  int idx = blockIdx.x*256 + threadIdx.x;
  if (idx < 38912) {
    f16 v = (f16)0.f;
    if (idx < 38400) {
      int n = idx / 600, k = idx % 600;
      if (k < 576) v = (f16)w[k*64 + n];
    }
    wt[idx] = v;
  } else if (idx < 38912 + 20480) {
    int id2 = idx - 38912;
    int j = id2 / 1280, f = id2 % 1280;
    pwT[id2] = (f16)pw[f*16 + j];
  }
}

// ---------------------------------------------------------------- conv2 as implicit GEMM (MFMA fp16) -> f16 out
__global__ __launch_bounds__(256) void k_conv2m(
    const f16* __restrict__ x1f, const f16* __restrict__ wt,
    const float* __restrict__ bias, f16* __restrict__ out)
{
  __shared__ f16 Bt[38912];
  const int tid = threadIdx.x;
  for (int it = 0; it < 19; ++it) {
    const f16* g = wt + it*2048 + tid*8;
    f16* l = Bt + it*2048 + tid*8;
    __builtin_amdgcn_global_load_lds(
        (const __attribute__((address_space(1))) void*)g,
        (__attribute__((address_space(3))) void*)l, 16, 0, 0);
  }
  __syncthreads();

  const int wave = tid >> 6, l = tid & 63;
  const int lrow = l & 15, lk = l >> 4;
  const int m0 = blockIdx.x*128 + wave*32;

  const int mA = m0 + lrow, mB = m0 + 16 + lrow;
  int bA = mA/10240, rA = mA%10240, ohA = rA/20, owA = rA%20;
  int bB = mB/10240, rB = mB%10240, ohB = rB/20, owB = rB%20;
  const f16* pA = x1f + ((size_t)((bA*1024 + ohA*2)*40 + owA*2))*64;
  const f16* pB = x1f + ((size_t)((bB*1024 + ohB*2)*40 + owB*2))*64;

  f32x4 acc[2][4];
#pragma unroll
  for (int i=0;i<2;i++)
#pragma unroll
    for (int j=0;j<4;j++) acc[i][j] = (f32x4){0.f,0.f,0.f,0.f};

  const f16x8 zero8 = {};
#pragma unroll
  for (int kk=0; kk<18; ++kk) {
    const int tap = kk >> 1;
    const int kh = tap/3, kw = tap%3;
    const int ci0 = ((kk&1)<<5) + lk*8;
    const int off = (kh*40 + kw)*64 + ci0;
    const bool okA = (ohA*2+kh < 1024) && (owA*2+kw < 40);
    const bool okB = (ohB*2+kh < 1024) && (owB*2+kw < 40);
    f16x8 a0 = okA ? *(const f16x8*)(pA + off) : zero8;
    f16x8 a1 = okB ? *(const f16x8*)(pB + off) : zero8;
#pragma unroll
    for (int nf=0; nf<4; ++nf) {
      f16x8 bb = *(const f16x8*)&Bt[(nf*16 + lrow)*600 + kk*32 + lk*8];
      acc[0][nf] = __builtin_amdgcn_mfma_f32_16x16x32_f16(a0, bb, acc[0][nf], 0,0,0);
      acc[1][nf] = __builtin_amdgcn_mfma_f32_16x16x32_f16(a1, bb, acc[1][nf], 0,0,0);
    }
  }
#pragma unroll
  for (int nf=0; nf<4; ++nf) {
    const int n = nf*16 + lrow;
    const float bi = bias[n];
#pragma unroll
    for (int mf=0; mf<2; ++mf)
#pragma unroll
      for (int r=0; r<4; ++r) {
        int mrow = m0 + mf*16 + lk*4 + r;
        out[(size_t)mrow*64 + n] = (f16)fmaxf(acc[mf][nf][r] + bi, 0.f);
      }
  }
}

// ---------------------------------------------------------------- proj as MFMA GEMM
__global__ __launch_bounds__(256) void k_projm(
    const f16* __restrict__ x2f, const f16* __restrict__ pwT,
    const float* __restrict__ pb, float* __restrict__ out)
{
  const int tid = threadIdx.x;
  const int wave = tid >> 6, l = tid & 63;
  const int lrow = l & 15, lk = l >> 4;
  const int m0 = (blockIdx.x*4 + wave)*16;
  const f16* pA = x2f + (size_t)(m0 + lrow)*1280 + lk*8;
  const f16* pB = pwT + (size_t)lrow*1280 + lk*8;
  f32x4 acc = {0.f,0.f,0.f,0.f};
#pragma unroll 4
  for (int k=0; k<40; ++k) {
    f16x8 a  = *(const f16x8*)(pA + k*32);
    f16x8 bb = *(const f16x8*)(pB + k*32);
    acc = __builtin_amdgcn_mfma_f32_16x16x32_f16(a, bb, acc, 0,0,0);
  }
#pragma unroll
  for (int r=0; r<4; ++r) {
    int row = m0 + lk*4 + r;
    out[(size_t)row*16 + lrow] = acc[r] + pb[lrow];
  }
}

// ------------------------------------------- primary caps (f16 out for uhat2)
__global__ __launch_bounds__(128) void k_primary(
    const float* __restrict__ emb0,
    const float* __restrict__ w0, const float* __restrict__ b0,
    const float* __restrict__ w1, const float* __restrict__ b1,
    const float* __restrict__ g, const float* __restrict__ be,
    const int* __restrict__ lens, f16* __restrict__ out)
{
  int bt = blockIdx.x;
  int b = bt >> 9, t = bt & 511;
  int tid = threadIdx.x;
  int c = tid & 7, j = tid >> 3;
  __shared__ float rows[3][16];
  __shared__ float red[4];
  if (tid < 48) {
    int kh = tid / 16, jj = tid % 16;
    int ts = t + kh - 1;
    rows[kh][jj] = (ts >= 0 && ts < 512) ? emb0[(b*512+ts)*16 + jj] : 0.f;
  }
  __syncthreads();
  float a0 = b0[c], a1 = b1[c];
#pragma unroll
  for (int kh=0; kh<3; kh++)
#pragma unroll
    for (int kw=0; kw<3; kw++) {
      int jj = j + kw - 1;
      if (jj < 0 || jj >= 16) continue;
      float xv = rows[kh][jj];
      a0 += xv * w0[(kh*3+kw)*8 + c];
      a1 += xv * w1[(kh*3+kw)*8 + c];
    }
  float e = fmaxf(a0, a1);
  int valid = (lens[b] + 3) >> 2;
  if (t >= valid) e = 0.f;
  float sq = e*e;
  sq += __shfl_xor(sq, 1, 8); sq += __shfl_xor(sq, 2, 8); sq += __shfl_xor(sq, 4, 8);
  float val = e * (sq / (1.f + sq)) * rsqrtf(sq + 1e-9f);
  float s1 = val, s2 = val*val;
#pragma unroll
  for (int m=1;m<64;m<<=1){ s1 += __shfl_xor(s1,m,64); s2 += __shfl_xor(s2,m,64); }
  if ((tid & 63) == 0){ red[(tid>>6)*2] = s1; red[(tid>>6)*2+1] = s2; }
  __syncthreads();
  float S1 = red[0]+red[2], S2 = red[1]+red[3];
  float mean = S1/128.f;
  float var  = S2/128.f - mean*mean;
  out[(size_t)bt*128 + tid] = (f16)((val-mean)*rsqrtf(var+1e-3f)*g[tid] + be[tid]);
}

// ---------------------------------------------------------------- LN over 128, f32 in -> f16 out
__global__ __launch_bounds__(128) void k_ln128(
    const float* __restrict__ in, const float* __restrict__ g,
    const float* __restrict__ be, f16* __restrict__ out)
{
  int bt = blockIdx.x, tid = threadIdx.x;
  float x = in[(size_t)bt*128 + tid];
  __shared__ float red[4];
  float s1 = x, s2 = x*x;
#pragma unroll
  for (int m=1;m<64;m<<=1){ s1 += __shfl_xor(s1,m,64); s2 += __shfl_xor(s2,m,64); }
  if ((tid & 63) == 0){ red[(tid>>6)*2] = s1; red[(tid>>6)*2+1] = s2; }
  __syncthreads();
  float S1 = red[0]+red[2], S2 = red[1]+red[3];
  float mean = S1/128.f;
  float var  = S2/128.f - mean*mean;
  out[(size_t)bt*128 + tid] = (f16)((x-mean)*rsqrtf(var+1e-3f)*g[tid] + be[tid]);
}

// ---------------------------------------------------------------- u_hat v2: lane = np, coalesced stores
// x f16 [b][512][16][8]; W f32 [80][CO][CD][8]; out f16 [b][512][NP][CD] (t-major, scan-friendly).
// Each thread owns one (n,o): W row cached in f16x2 regs, amortized over 64 t-iterations.
template<int CO, int CD>
__global__ __launch_bounds__(256) void k_uhat2(
    const f16* __restrict__ xf, const float* __restrict__ W,
    const float* __restrict__ Bs, f16* __restrict__ out)
{
  constexpr int NP = 80*CO;
  constexpr int NPB = NP/256;
  const int tid = threadIdx.x;
  const int npb = blockIdx.x % NPB;
  const int btc = blockIdx.x / NPB;     // b*8 + tc
  const int b = btc >> 3, tc = btc & 7;
  const int np = npb*256 + tid;
  const int n = np / CO, o = np % CO;   // CO pow2 -> shifts
  const int k = n >> 4, i = n & 15;

  const float* Wr = W + ((size_t)n*CO + o)*CD*8;
  f16x2 wpk[CD*4];
#pragma unroll
  for (int p=0;p<CD;p++)
#pragma unroll
    for (int z=0;z<4;z++)
      wpk[p*4+z] = (f16x2){ (f16)Wr[p*8+2*z], (f16)Wr[p*8+2*z+1] };
  float bias[CD];
  const float* Br = Bs + ((size_t)n*CO + o)*CD;
#pragma unroll
  for (int p=0;p<CD;p++) bias[p] = Br[p];

  const f16* xb = xf + (size_t)b*512*128;

  for (int tt=0; tt<64; ++tt) {
    const int t = tc*64 + tt;
    const int ts = t + k - 2;
    f16x8 x8 = {};
    if (ts >= 0 && ts < 512) x8 = *(const f16x8*)(xb + (ts*16 + i)*8);
    const f16x2* xp = (const f16x2*)&x8;
    alignas(16) f16 res[CD];
#pragma unroll
    for (int p=0;p<CD;p++) {
      float a = bias[p];
#pragma unroll
      for (int z=0;z<4;z++)
        a = __builtin_amdgcn_fdot2(wpk[p*4+z], xp[z], a, false);
      res[p] = (f16)a;
    }
    f16* op = out + ((size_t)(b*512 + t)*NP + np)*CD;
    *(uint4*)op = *(const uint4*)res;
    if constexpr (CD==16) *((uint4*)op+1) = *((const uint4*)res+1);
  }
}

// ---------------------------------------------------------------- routing scan v8 (known-good 707 µs config)
template<int CO, int CD, int NW, bool MASK>
__global__ __launch_bounds__(NW*64, 1) void k_scan8(
    const f16* __restrict__ uh, float* __restrict__ vseq, int T)
{
  constexpr int TH = NW*64;
  constexpr int JPW = 64/CO;                 // jj groups per wave (2 or 4)
  constexpr int NJ  = NW*JPW;                // 16 (L1) or 40 (L0)
  constexpr int SLOTS = 80/NJ;               // 5 (L1) or 2 (L0) — exact
  constexpr int NP = 80*CO;
  constexpr int QN = CO*CD;                  // 512 (L1) / 128 (L0)
  constexpr int NV = CD/8;
  constexpr int PSTR = (CD==16) ? 20 : 12;   // part row stride (f32), padded
  constexpr int SSTR = (CD==16) ? 12 : 4;    // smat row stride (u32)

  __shared__ float    part[NW*CO*PSTR];
  __shared__ unsigned smat[CO*SSTR];

  const int b = blockIdx.x;
  const int tid = threadIdx.x;
  const int wv = tid >> 6, lane = tid & 63;
  const int o  = (CO==32) ? ((lane & 15) | (((lane>>5)&1)<<4)) : (lane & 15);
  const int jw = (CO==32) ? ((lane>>4)&1) : (lane>>4);
  const int jj = jw + JPW*wv;

  const f16* __restrict__ ubase = uh + (size_t)b*T*NP*CD;
  float* __restrict__ vb = vseq + (size_t)b*T*QN;

  unsigned uoff[SLOTS];
#pragma unroll
  for (int s=0;s<SLOTS;s++)
    uoff[s] = (unsigned)((jj + NJ*s)*CO + o)*CD;

  union VHU { unsigned w[CD/2]; f16x2 h2[CD/2]; uint4 q4[NV]; } vh;
#pragma unroll
  for (int q=0;q<CD/2;q++) vh.w[q] = 0u;

  f16x8 UA[SLOTS][NV], UB[SLOTS][NV];

#define LOADU(U, PTR) do {                                                   \
  _Pragma("unroll") for (int s_=0; s_<SLOTS; ++s_)                           \
  _Pragma("unroll") for (int q_=0; q_<NV; ++q_)                              \
    U[s_][q_] = *(const f16x8*)((PTR) + uoff[s_] + q_*8);                    \
} while(0)

#define STEP(U, TT) do {                                                     \
  float c_[SLOTS];                                                           \
  _Pragma("unroll") for (int s_=0; s_<SLOTS; ++s_) {                         \
    float a_ = 0.f;                                                          \
    _Pragma("unroll") for (int q_=0; q_<NV; ++q_) {                          \
      const f16x2* u2_ = (const f16x2*)&U[s_][q_];                           \
      _Pragma("unroll") for (int z_=0; z_<4; ++z_)                           \
        a_ = __builtin_amdgcn_fdot2(u2_[z_], vh.h2[q_*4+z_], a_, false);     \
    }                                                                        \
    float ex_ = __builtin_amdgcn_exp2f(a_);   /* v stored pre-scaled */      \
    if (MASK && o == 0) ex_ = 0.f;                                           \
    float sm_ = ex_;                                                         \
    sm_ = dpp_add<0x121>(sm_); sm_ = dpp_add<0x122>(sm_);                    \
    sm_ = dpp_add<0x124>(sm_); sm_ = dpp_add<0x128>(sm_);                    \
    if (CO == 32) sm_ = pl32_add(sm_);                                       \
    c_[s_] = ex_ * __builtin_amdgcn_rcpf(sm_);                               \
  }                                                                          \
  /* PV: packed f16 fma (v_pk_fma_f16), one unpack to f32 afterwards */      \
  f16x2 pp2_[CD/2];                                                          \
  _Pragma("unroll") for (int r_=0; r_<CD/2; ++r_) pp2_[r_] = (f16x2){0,0};   \
  _Pragma("unroll") for (int s_=0; s_<SLOTS; ++s_) {                         \
    f16 ch_ = (f16)c_[s_];                                                   \
    f16x2 c2_ = { ch_, ch_ };                                                \
    _Pragma("unroll") for (int q_=0; q_<NV; ++q_) {                          \
      const f16x2* u2_ = (const f16x2*)&U[s_][q_];                           \
      _Pragma("unroll") for (int z_=0; z_<4; ++z_)                           \
        pp2_[q_*4+z_] += u2_[z_] * c2_;                                      \
    }                                                                        \
  }                                                                          \
  float pp_[CD];                                                             \
  _Pragma("unroll") for (int r_=0; r_<CD/2; ++r_) {                          \
    pp_[2*r_]   = (float)pp2_[r_][0];                                        \
    pp_[2*r_+1] = (float)pp2_[r_][1];                                        \
  }                                                                          \
  _Pragma("unroll") for (int p_=0; p_<CD; ++p_) {                            \
    pp_[p_] = swap16_add(pp_[p_]);                                           \
    if (CO == 16) pp_[p_] = pl32_add(pp_[p_]);                               \
  }                                                                          \
  if (jw == 0) {                                                             \
    float* pr_ = &part[(wv*CO + o)*PSTR];                                    \
    _Pragma("unroll") for (int p_=0; p_<CD; p_+=4) {                         \
      f32x4 w4_ = { pp_[p_], pp_[p_+1], pp_[p_+2], pp_[p_+3] };              \
      *(f32x4*)(pr_ + p_) = w4_;                                             \
    }                                                                        \
  }                                                                          \
  lds_barrier();                                                             \
  if (QN == TH || tid < QN) {                                                \
    const int p2_ = tid & (CD-1), o2_ = tid >> ((CD==16)?4:3);               \
    float sv_ = 0.f;                                                         \
    _Pragma("unroll") for (int w_=0; w_<NW; ++w_)                            \
      sv_ += part[(w_*CO + o2_)*PSTR + p2_];                                 \
    float sq_ = sv_*sv_;                                                     \
    if (CD == 16) {                                                          \
      sq_ = dpp_add<0x121>(sq_); sq_ = dpp_add<0x122>(sq_);                  \
      sq_ = dpp_add<0x124>(sq_); sq_ = dpp_add<0x128>(sq_);                  \
    } else {                                                                 \
      sq_ = dpp_add<0xB1>(sq_); sq_ = dpp_add<0x4E>(sq_);                    \
      sq_ = dpp_add<0x141>(sq_);                                             \
    }                                                                        \
    float f_ = sq_ * __builtin_amdgcn_rcpf(1.f + sq_) * rsqrtf(sq_ + 1e-9f); \
    float vn_ = sv_ * f_;                                                    \
    vb[(size_t)(TT)*QN + tid] = vn_;                                         \
    float vn1_ = dpp_get<0xB1>(vn_);                                         \
    if ((p2_ & 1) == 0) {                                                    \
      union { f16x2 h2; unsigned w; } pk_;                                   \
      pk_.h2 = (f16x2){ (f16)(vn_*1.44269504f), (f16)(vn1_*1.44269504f) };   \
      smat[o2_*SSTR + (p2_>>1)] = pk_.w;                                     \
    }                                                                        \
  }                                                                          \
  lds_barrier();                                                             \
  _Pragma("unroll") for (int q_=0; q_<NV; ++q_)                              \
    vh.q4[q_] = *(const uint4*)&smat[o*SSTR + q_*4];                         \
} while(0)

  const size_t ST = (size_t)NP*CD;
  const f16* pcur = ubase;
  LOADU(UA, pcur);
  for (int t=0; t<T; t+=2) {
    LOADU(UB, pcur + ST);          // tile t+1
    STEP(UA, t);
    LOADU(UA, pcur + 2*ST);        // tile t+2 (tail overread stays in ws)
    STEP(UB, t+1);
    pcur += 2*ST;
  }
#undef LOADU
#undef STEP
}

// ---------------------------------------------------------------- final: LN512 -> length -> LN32
__global__ __launch_bounds__(512) void k_final(
    const float* __restrict__ v1,
    const float* __restrict__ g1, const float* __restrict__ b1,
    const float* __restrict__ g2, const float* __restrict__ b2,
    float* __restrict__ out)
{
  int bt = blockIdx.x;
  int tid = threadIdx.x;
  float x = v1[(size_t)bt*512 + tid];
  __shared__ float red[16];
  __shared__ float Ls[32];
  float s1 = x, s2 = x*x;
#pragma unroll
  for (int m=1;m<64;m<<=1){ s1 += __shfl_xor(s1,m,64); s2 += __shfl_xor(s2,m,64); }
  if ((tid & 63) == 0){ red[(tid>>6)*2] = s1; red[(tid>>6)*2+1] = s2; }
  __syncthreads();
  float S1 = 0.f, S2 = 0.f;
#pragma unroll
  for (int i=0;i<8;i++){ S1 += red[2*i]; S2 += red[2*i+1]; }
  float mean = S1/512.f, var = S2/512.f - mean*mean;
  float y = (x-mean)*rsqrtf(var+1e-3f)*g1[tid] + b1[tid];
  float ss = y*y;
  ss += __shfl_xor(ss,1,16); ss += __shfl_xor(ss,2,16);
  ss += __shfl_xor(ss,4,16); ss += __shfl_xor(ss,8,16);
  float L = sqrtf(ss + 1e-9f);
  if ((tid & 15) == 0) Ls[tid >> 4] = L;
  __syncthreads();
  if (tid < 32) {
    float l = Ls[tid];
    float t1 = l, t2 = l*l;
#pragma unroll
    for (int m=1;m<32;m<<=1){ t1 += __shfl_xor(t1,m,32); t2 += __shfl_xor(t2,m,32); }
    float mn = t1/32.f, vr = t2/32.f - mn*mn;
    out[(size_t)bt*32 + tid] = (l-mn)*rsqrtf(vr+1e-3f)*g2[tid] + b2[tid];
  }
}

// ---------------------------------------------------------------- workspace layout
static const size_t OFF_X1F   = 0;            // 20,971,520 B f16 [4,1024,40,64]
static const size_t OFF_WT16  = 20971520;     //     77,824 B f16 [64][600]
static const size_t OFF_PWT   = 21049344;     //     40,960 B f16 [16][1280]
static const size_t OFF_X2F   = 21090304;     //  5,242,880 B f16 [2048][1280]
static const size_t OFF_EMB0  = 26333184;     //    131,072 B f32 [2048][16]
static const size_t OFF_UH0   = 26464256;     // 41,943,040 B f16 [4,512,1280,8]
static const size_t OFF_UH1   = 0;            // 167,772,160 B f16 [4,512,2560,16] (reuses dead frontend)
static const size_t OFF_EMBLN = 167772160;    //    524,288 B f16 [2048][128]
static const size_t OFF_V0    = 167772160;    //  1,048,576 B f32 (reuses EMBLN slot after uhat0)
static const size_t OFF_V0LN  = 168820736;    //    524,288 B f16
static const size_t OFF_V1    = 169869312;    //  4,194,304 B f32 [4,512,32,16]
static const size_t WS_NEED   = 174063616;

extern "C" void kernel_launch(void* const* d_in, const int* in_sizes, int n_in,
                              void* d_out, int out_size, void* d_ws, size_t ws_size,
                              hipStream_t stream) {
  (void)in_sizes; (void)n_in; (void)out_size;
  if (ws_size < WS_NEED) return;

  const float* inputs = (const float*)d_in[0];
  const int*   lens   = (const int*)d_in[1];
  const float* c1w=(const float*)d_in[2],  *c1b=(const float*)d_in[3];
  const float* c2w=(const float*)d_in[4],  *c2b=(const float*)d_in[5];
  const float* pw =(const float*)d_in[6],  *pb =(const float*)d_in[7];
  const float* e0w=(const float*)d_in[8],  *e0b=(const float*)d_in[9];
  const float* e1w=(const float*)d_in[10], *e1b=(const float*)d_in[11];
  const float* lnig=(const float*)d_in[12],*lnib=(const float*)d_in[13];
  const float* W0=(const float*)d_in[14],  *B0=(const float*)d_in[15];
  const float* W1=(const float*)d_in[16],  *B1=(const float*)d_in[17];
  const float* lnm0g=(const float*)d_in[18],*lnm0b=(const float*)d_in[19];
  const float* lnm1g=(const float*)d_in[20],*lnm1b=(const float*)d_in[21];
  const float* lnog=(const float*)d_in[22], *lnob=(const float*)d_in[23];

  char* ws = (char*)d_ws;
  f16*   x1f   = (f16*)  (ws + OFF_X1F);
  f16*   wt16  = (f16*)  (ws + OFF_WT16);
  f16*   pwT   = (f16*)  (ws + OFF_PWT);
  f16*   x2f   = (f16*)  (ws + OFF_X2F);
  float* emb0  = (float*)(ws + OFF_EMB0);
  f16*   uh0   = (f16*)  (ws + OFF_UH0);
  f16*   uh1   = (f16*)  (ws + OFF_UH1);
  f16*   embln = (f16*)  (ws + OFF_EMBLN);
  float* v0    = (float*)(ws + OFF_V0);
  f16*   v0ln  = (f16*)  (ws + OFF_V0LN);
  float* v1    = (float*)(ws + OFF_V1);

  k_conv1<<<40960, 256, 0, stream>>>(inputs, c1w, c1b, x1f);
  k_wcvt2<<<232, 256, 0, stream>>>(c2w, pw, wt16, pwT);
  k_conv2m<<<320, 256, 0, stream>>>(x1f, wt16, c2b, x2f);
  k_projm<<<32, 256, 0, stream>>>(x2f, pwT, pb, emb0);
  k_primary<<<2048, 128, 0, stream>>>(emb0, e0w, e0b, e1w, e1b, lnig, lnib, lens, embln);
  k_uhat2<16,8><<<160, 256, 0, stream>>>(embln, W0, B0, uh0);
  k_scan8<16,8,10,false><<<4, 640, 0, stream>>>(uh0, v0, 512);
  k_ln128<<<2048, 128, 0, stream>>>(v0, lnm0g, lnm0b, v0ln);
  k_uhat2<32,16><<<320, 256, 0, stream>>>(v0ln, W1, B1, uh1);
  k_scan8<32,16,8,true><<<4, 512, 0, stream>>>(uh1, v1, 512);
  k_final<<<2048, 512, 0, stream>>>(v1, lnm1g, lnm1b, lnog, lnob, (float*)d_out);
}

// Round 14
// 1089.661 us; speedup vs baseline: 2.1391x; 1.1994x over previous
//
#include <hip/hip_runtime.h>
#include <hip/hip_fp16.h>

typedef _Float16 f16;
typedef _Float16 f16x2 __attribute__((ext_vector_type(2)));
typedef _Float16 f16x8 __attribute__((ext_vector_type(8)));
typedef float f32x2 __attribute__((ext_vector_type(2)));
typedef float f32x4 __attribute__((ext_vector_type(4)));

#define DEV static __device__ __forceinline__

// LDS-only barrier — keeps global loads/stores in flight.
DEV void lds_barrier() {
  asm volatile("s_waitcnt lgkmcnt(0)" ::: "memory");
  __builtin_amdgcn_s_barrier();
  asm volatile("" ::: "memory");
}

// ---- VALU cross-lane reduction helpers (no DS pipe) ----
template<int CTRL>
DEV float dpp_add(float x) {
  int y = __builtin_amdgcn_update_dpp(0, __builtin_bit_cast(int, x), CTRL, 0xf, 0xf, false);
  return x + __builtin_bit_cast(float, y);
}
DEV float pl32_add(float x) {  // x + x[lane^32]
  unsigned xi = __builtin_bit_cast(unsigned, x);
  auto r = __builtin_amdgcn_permlane32_swap(xi, xi, false, false);
  return __builtin_bit_cast(float, (unsigned)r[0]) + __builtin_bit_cast(float, (unsigned)r[1]);
}
// packed f16x2 cross-lane adds (v_pk_add_f16 after permlane swap)
DEV f16x2 swap16_pkadd(f16x2 x) {  // x + x[lane^16], packed
#if __has_builtin(__builtin_amdgcn_permlane16_swap)
  unsigned xi = __builtin_bit_cast(unsigned, x);
  auto r = __builtin_amdgcn_permlane16_swap(xi, xi, false, false);
  return __builtin_bit_cast(f16x2, (unsigned)r[0]) + __builtin_bit_cast(f16x2, (unsigned)r[1]);
#else
  int y = __builtin_amdgcn_ds_swizzle(__builtin_bit_cast(int, x), 0x401F);
  return x + __builtin_bit_cast(f16x2, y);
#endif
}
DEV f16x2 pl32_pkadd(f16x2 x) {    // x + x[lane^32], packed
  unsigned xi = __builtin_bit_cast(unsigned, x);
  auto r = __builtin_amdgcn_permlane32_swap(xi, xi, false, false);
  return __builtin_bit_cast(f16x2, (unsigned)r[0]) + __builtin_bit_cast(f16x2, (unsigned)r[1]);
}

// ---------------------------------------------------------------- conv1
__global__ __launch_bounds__(256) void k_conv1(
    const float* __restrict__ in, const float* __restrict__ w,
    const float* __restrict__ bias, f16* __restrict__ out)
{
  int idx = blockIdx.x*256 + threadIdx.x;
  int co = idx & 63;
  int ow = (idx >> 6) % 40;
  int oh = ((idx >> 6) / 40) % 1024;
  int b  = idx / (64*40*1024);
  float acc = bias[co];
#pragma unroll
  for (int kh=0; kh<3; kh++) {
    int ih = oh*2 + kh;
    if (ih >= 2048) continue;
#pragma unroll
    for (int kw=0; kw<3; kw++) {
      int iw = ow*2 + kw;
      if (iw >= 80) continue;
      acc += in[(b*2048 + ih)*80 + iw] * w[(kh*3+kw)*64 + co];
    }
  }
  out[idx] = (f16)fmaxf(acc, 0.f);
}

// ---------------------------------------------------------------- merged weight converts
__global__ __launch_bounds__(256) void k_wcvt2(
    const float* __restrict__ w, const float* __restrict__ pw,
    f16* __restrict__ wt, f16* __restrict__ pwT)
{
  int idx = blockIdx.x*256 + threadIdx.x;
  if (idx < 38912) {
    f16 v = (f16)0.f;
    if (idx < 38400) {
      int n = idx / 600, k = idx % 600;
      if (k < 576) v = (f16)w[k*64 + n];
    }
    wt[idx] = v;
  } else if (idx < 38912 + 20480) {
    int id2 = idx - 38912;
    int j = id2 / 1280, f = id2 % 1280;
    pwT[id2] = (f16)pw[f*16 + j];
  }
}

// ---------------------------------------------------------------- conv2 as implicit GEMM (MFMA fp16) -> f16 out
__global__ __launch_bounds__(256) void k_conv2m(
    const f16* __restrict__ x1f, const f16* __restrict__ wt,
    const float* __restrict__ bias, f16* __restrict__ out)
{
  __shared__ f16 Bt[38912];
  const int tid = threadIdx.x;
  for (int it = 0; it < 19; ++it) {
    const f16* g = wt + it*2048 + tid*8;
    f16* l = Bt + it*2048 + tid*8;
    __builtin_amdgcn_global_load_lds(
        (const __attribute__((address_space(1))) void*)g,
        (__attribute__((address_space(3))) void*)l, 16, 0, 0);
  }
  __syncthreads();

  const int wave = tid >> 6, l = tid & 63;
  const int lrow = l & 15, lk = l >> 4;
  const int m0 = blockIdx.x*128 + wave*32;

  const int mA = m0 + lrow, mB = m0 + 16 + lrow;
  int bA = mA/10240, rA = mA%10240, ohA = rA/20, owA = rA%20;
  int bB = mB/10240, rB = mB%10240, ohB = rB/20, owB = rB%20;
  const f16* pA = x1f + ((size_t)((bA*1024 + ohA*2)*40 + owA*2))*64;
  const f16* pB = x1f + ((size_t)((bB*1024 + ohB*2)*40 + owB*2))*64;

  f32x4 acc[2][4];
#pragma unroll
  for (int i=0;i<2;i++)
#pragma unroll
    for (int j=0;j<4;j++) acc[i][j] = (f32x4){0.f,0.f,0.f,0.f};

  const f16x8 zero8 = {};
#pragma unroll
  for (int kk=0; kk<18; ++kk) {
    const int tap = kk >> 1;
    const int kh = tap/3, kw = tap%3;
    const int ci0 = ((kk&1)<<5) + lk*8;
    const int off = (kh*40 + kw)*64 + ci0;
    const bool okA = (ohA*2+kh < 1024) && (owA*2+kw < 40);
    const bool okB = (ohB*2+kh < 1024) && (owB*2+kw < 40);
    f16x8 a0 = okA ? *(const f16x8*)(pA + off) : zero8;
    f16x8 a1 = okB ? *(const f16x8*)(pB + off) : zero8;
#pragma unroll
    for (int nf=0; nf<4; ++nf) {
      f16x8 bb = *(const f16x8*)&Bt[(nf*16 + lrow)*600 + kk*32 + lk*8];
      acc[0][nf] = __builtin_amdgcn_mfma_f32_16x16x32_f16(a0, bb, acc[0][nf], 0,0,0);
      acc[1][nf] = __builtin_amdgcn_mfma_f32_16x16x32_f16(a1, bb, acc[1][nf], 0,0,0);
    }
  }
#pragma unroll
  for (int nf=0; nf<4; ++nf) {
    const int n = nf*16 + lrow;
    const float bi = bias[n];
#pragma unroll
    for (int mf=0; mf<2; ++mf)
#pragma unroll
      for (int r=0; r<4; ++r) {
        int mrow = m0 + mf*16 + lk*4 + r;
        out[(size_t)mrow*64 + n] = (f16)fmaxf(acc[mf][nf][r] + bi, 0.f);
      }
  }
}

// ---------------------------------------------------------------- proj as MFMA GEMM
__global__ __launch_bounds__(256) void k_projm(
    const f16* __restrict__ x2f, const f16* __restrict__ pwT,
    const float* __restrict__ pb, float* __restrict__ out)
{
  const int tid = threadIdx.x;
  const int wave = tid >> 6, l = tid & 63;
  const int lrow = l & 15, lk = l >> 4;
  const int m0 = (blockIdx.x*4 + wave)*16;
  const f16* pA = x2f + (size_t)(m0 + lrow)*1280 + lk*8;
  const f16* pB = pwT + (size_t)lrow*1280 + lk*8;
  f32x4 acc = {0.f,0.f,0.f,0.f};
#pragma unroll 4
  for (int k=0; k<40; ++k) {
    f16x8 a  = *(const f16x8*)(pA + k*32);
    f16x8 bb = *(const f16x8*)(pB + k*32);
    acc = __builtin_amdgcn_mfma_f32_16x16x32_f16(a, bb, acc, 0,0,0);
  }
#pragma unroll
  for (int r=0; r<4; ++r) {
    int row = m0 + lk*4 + r;
    out[(size_t)row*16 + lrow] = acc[r] + pb[lrow];
  }
}

// ------------------------------------------- primary caps (f16 out for uhat2)
__global__ __launch_bounds__(128) void k_primary(
    const float* __restrict__ emb0,
    const float* __restrict__ w0, const float* __restrict__ b0,
    const float* __restrict__ w1, const float* __restrict__ b1,
    const float* __restrict__ g, const float* __restrict__ be,
    const int* __restrict__ lens, f16* __restrict__ out)
{
  int bt = blockIdx.x;
  int b = bt >> 9, t = bt & 511;
  int tid = threadIdx.x;
  int c = tid & 7, j = tid >> 3;
  __shared__ float rows[3][16];
  __shared__ float red[4];
  if (tid < 48) {
    int kh = tid / 16, jj = tid % 16;
    int ts = t + kh - 1;
    rows[kh][jj] = (ts >= 0 && ts < 512) ? emb0[(b*512+ts)*16 + jj] : 0.f;
  }
  __syncthreads();
  float a0 = b0[c], a1 = b1[c];
#pragma unroll
  for (int kh=0; kh<3; kh++)
#pragma unroll
    for (int kw=0; kw<3; kw++) {
      int jj = j + kw - 1;
      if (jj < 0 || jj >= 16) continue;
      float xv = rows[kh][jj];
      a0 += xv * w0[(kh*3+kw)*8 + c];
      a1 += xv * w1[(kh*3+kw)*8 + c];
    }
  float e = fmaxf(a0, a1);
  int valid = (lens[b] + 3) >> 2;
  if (t >= valid) e = 0.f;
  float sq = e*e;
  sq += __shfl_xor(sq, 1, 8); sq += __shfl_xor(sq, 2, 8); sq += __shfl_xor(sq, 4, 8);
  float val = e * (sq / (1.f + sq)) * rsqrtf(sq + 1e-9f);
  float s1 = val, s2 = val*val;
#pragma unroll
  for (int m=1;m<64;m<<=1){ s1 += __shfl_xor(s1,m,64); s2 += __shfl_xor(s2,m,64); }
  if ((tid & 63) == 0){ red[(tid>>6)*2] = s1; red[(tid>>6)*2+1] = s2; }
  __syncthreads();
  float S1 = red[0]+red[2], S2 = red[1]+red[3];
  float mean = S1/128.f;
  float var  = S2/128.f - mean*mean;
  out[(size_t)bt*128 + tid] = (f16)((val-mean)*rsqrtf(var+1e-3f)*g[tid] + be[tid]);
}

// ---------------------------------------------------------------- LN over 128, f32 in -> f16 out
__global__ __launch_bounds__(128) void k_ln128(
    const float* __restrict__ in, const float* __restrict__ g,
    const float* __restrict__ be, f16* __restrict__ out)
{
  int bt = blockIdx.x, tid = threadIdx.x;
  float x = in[(size_t)bt*128 + tid];
  __shared__ float red[4];
  float s1 = x, s2 = x*x;
#pragma unroll
  for (int m=1;m<64;m<<=1){ s1 += __shfl_xor(s1,m,64); s2 += __shfl_xor(s2,m,64); }
  if ((tid & 63) == 0){ red[(tid>>6)*2] = s1; red[(tid>>6)*2+1] = s2; }
  __syncthreads();
  float S1 = red[0]+red[2], S2 = red[1]+red[3];
  float mean = S1/128.f;
  float var  = S2/128.f - mean*mean;
  out[(size_t)bt*128 + tid] = (f16)((x-mean)*rsqrtf(var+1e-3f)*g[tid] + be[tid]);
}

// ---------------------------------------------------------------- u_hat v2: lane = np, coalesced stores
template<int CO, int CD>
__global__ __launch_bounds__(256) void k_uhat2(
    const f16* __restrict__ xf, const float* __restrict__ W,
    const float* __restrict__ Bs, f16* __restrict__ out)
{
  constexpr int NP = 80*CO;
  constexpr int NPB = NP/256;
  const int tid = threadIdx.x;
  const int npb = blockIdx.x % NPB;
  const int btc = blockIdx.x / NPB;     // b*8 + tc
  const int b = btc >> 3, tc = btc & 7;
  const int np = npb*256 + tid;
  const int n = np / CO, o = np % CO;
  const int k = n >> 4, i = n & 15;

  const float* Wr = W + ((size_t)n*CO + o)*CD*8;
  f16x2 wpk[CD*4];
#pragma unroll
  for (int p=0;p<CD;p++)
#pragma unroll
    for (int z=0;z<4;z++)
      wpk[p*4+z] = (f16x2){ (f16)Wr[p*8+2*z], (f16)Wr[p*8+2*z+1] };
  float bias[CD];
  const float* Br = Bs + ((size_t)n*CO + o)*CD;
#pragma unroll
  for (int p=0;p<CD;p++) bias[p] = Br[p];

  const f16* xb = xf + (size_t)b*512*128;

  for (int tt=0; tt<64; ++tt) {
    const int t = tc*64 + tt;
    const int ts = t + k - 2;
    f16x8 x8 = {};
    if (ts >= 0 && ts < 512) x8 = *(const f16x8*)(xb + (ts*16 + i)*8);
    const f16x2* xp = (const f16x2*)&x8;
    alignas(16) f16 res[CD];
#pragma unroll
    for (int p=0;p<CD;p++) {
      float a = bias[p];
#pragma unroll
      for (int z=0;z<4;z++)
        a = __builtin_amdgcn_fdot2(wpk[p*4+z], xp[z], a, false);
      res[p] = (f16)a;
    }
    f16* op = out + ((size_t)(b*512 + t)*NP + np)*CD;
    *(uint4*)op = *(const uint4*)res;
    if constexpr (CD==16) *((uint4*)op+1) = *((const uint4*)res+1);
  }
}

// ---------------------------------------------------------------- routing scan v11
// = v8 with fully-PACKED f16 PV reduce path: in-wave jw-reduce via permlane+pk_add
// (no f32 unpack), part[] stores packed u32, reduce phase QN/2 threads doing
// packed pk_adds + fdot2 squash. Cuts ~50 VALU insts/thread/step + halves the
// reduce-phase DS traffic. Accuracy: +~8 f16 adds on O(1) values (budget ok).
template<int CO, int CD, int NW, bool MASK>
__global__ __launch_bounds__(NW*64, 1) void k_scan11(
    const f16* __restrict__ uh, float* __restrict__ vseq, int T)
{
  constexpr int JPW = 64/CO;                 // jj groups per wave (2 or 4)
  constexpr int NJ  = NW*JPW;                // 16 (L1) or 40 (L0)
  constexpr int SLOTS = 80/NJ;               // 5 (L1) or 2 (L0) — exact
  constexpr int NP = 80*CO;
  constexpr int QN = CO*CD;                  // 512 (L1) / 128 (L0)
  constexpr int NV = CD/8;
  constexpr int P2 = CD/2;                   // u32 pairs per capsule
  constexpr int PSTR2 = (CD==16) ? 12 : 8;   // part row stride (u32), 16B-aligned
  constexpr int SSTR2 = 12;                  // smat row stride (u32), 48B rows

  __shared__ unsigned partk[NW*CO*PSTR2];
  __shared__ unsigned smat[CO*SSTR2];

  const int b = blockIdx.x;
  const int tid = threadIdx.x;
  const int wv = tid >> 6, lane = tid & 63;
  const int o  = (CO==32) ? ((lane & 15) | (((lane>>5)&1)<<4)) : (lane & 15);
  const int jw = (CO==32) ? ((lane>>4)&1) : (lane>>4);
  const int jj = jw + JPW*wv;

  const f16* __restrict__ ubase = uh + (size_t)b*T*NP*CD;
  float* __restrict__ vb = vseq + (size_t)b*T*QN;

  unsigned uoff[SLOTS];
#pragma unroll
  for (int s=0;s<SLOTS;s++)
    uoff[s] = (unsigned)((jj + NJ*s)*CO + o)*CD;

  union VHU { unsigned w[P2]; f16x2 h2[P2]; uint4 q4[NV]; } vh;
#pragma unroll
  for (int q=0;q<P2;q++) vh.w[q] = 0u;

  f16x8 UA[SLOTS][NV], UB[SLOTS][NV];

#define LOADU(U, PTR) do {                                                   \
  _Pragma("unroll") for (int s_=0; s_<SLOTS; ++s_)                           \
  _Pragma("unroll") for (int q_=0; q_<NV; ++q_)                              \
    U[s_][q_] = *(const f16x8*)((PTR) + uoff[s_] + q_*8);                    \
} while(0)

#define STEP(U, TT) do {                                                     \
  float c_[SLOTS];                                                           \
  _Pragma("unroll") for (int s_=0; s_<SLOTS; ++s_) {                         \
    float a_ = 0.f;                                                          \
    _Pragma("unroll") for (int q_=0; q_<NV; ++q_) {                          \
      const f16x2* u2_ = (const f16x2*)&U[s_][q_];                           \
      _Pragma("unroll") for (int z_=0; z_<4; ++z_)                           \
        a_ = __builtin_amdgcn_fdot2(u2_[z_], vh.h2[q_*4+z_], a_, false);     \
    }                                                                        \
    float ex_ = __builtin_amdgcn_exp2f(a_);   /* v stored pre-scaled */      \
    if (MASK && o == 0) ex_ = 0.f;                                           \
    float sm_ = ex_;                                                         \
    sm_ = dpp_add<0x121>(sm_); sm_ = dpp_add<0x122>(sm_);                    \
    sm_ = dpp_add<0x124>(sm_); sm_ = dpp_add<0x128>(sm_);                    \
    if (CO == 32) sm_ = pl32_add(sm_);                                       \
    c_[s_] = ex_ * __builtin_amdgcn_rcpf(sm_);                               \
  }                                                                          \
  /* PV: packed f16 fma; stay packed through the cross-lane reduce */        \
  f16x2 pp2_[P2];                                                            \
  _Pragma("unroll") for (int r_=0; r_<P2; ++r_) pp2_[r_] = (f16x2){0,0};     \
  _Pragma("unroll") for (int s_=0; s_<SLOTS; ++s_) {                         \
    f16 ch_ = (f16)c_[s_];                                                   \
    f16x2 c2_ = { ch_, ch_ };                                                \
    _Pragma("unroll") for (int q_=0; q_<NV; ++q_) {                          \
      const f16x2* u2_ = (const f16x2*)&U[s_][q_];                           \
      _Pragma("unroll") for (int z_=0; z_<4; ++z_)                           \
        pp2_[q_*4+z_] += u2_[z_] * c2_;                                      \
    }                                                                        \
  }                                                                          \
  _Pragma("unroll") for (int r_=0; r_<P2; ++r_) {                            \
    pp2_[r_] = swap16_pkadd(pp2_[r_]);                                       \
    if (CO == 16) pp2_[r_] = pl32_pkadd(pp2_[r_]);                           \
  }                                                                          \
  if (jw == 0) {                                                             \
    unsigned* pr_ = &partk[(wv*CO + o)*PSTR2];                               \
    *(uint4*)pr_ = *(const uint4*)&pp2_[0];                                  \
    if (CD == 16) *(uint4*)(pr_ + 4) = *(const uint4*)&pp2_[4];              \
  }                                                                          \
  lds_barrier();                                                             \
  if (tid < CO*P2) {                                                         \
    const int pp_ = tid & (P2-1), o2_ = tid / P2;                            \
    f16x2 sv2_ = (f16x2){0,0};                                               \
    _Pragma("unroll") for (int w_=0; w_<NW; ++w_)                            \
      sv2_ += __builtin_bit_cast(f16x2, partk[(w_*CO + o2_)*PSTR2 + pp_]);   \
    float sq_ = __builtin_amdgcn_fdot2(sv2_, sv2_, 0.f, false);              \
    sq_ = dpp_add<0xB1>(sq_); sq_ = dpp_add<0x4E>(sq_);                      \
    if (CD == 16) sq_ = dpp_add<0x141>(sq_);                                 \
    float f_ = sq_ * __builtin_amdgcn_rcpf(1.f + sq_) * rsqrtf(sq_ + 1e-9f); \
    f32x2 vo_ = { (float)sv2_[0] * f_, (float)sv2_[1] * f_ };                \
    *(f32x2*)(vb + (size_t)(TT)*QN + o2_*CD + 2*pp_) = vo_;                  \
    f16 fl_ = (f16)(f_ * 1.44269504f);                                       \
    f16x2 vhp_ = sv2_ * (f16x2){fl_, fl_};                                   \
    smat[o2_*SSTR2 + pp_] = __builtin_bit_cast(unsigned, vhp_);              \
  }                                                                          \
  lds_barrier();                                                             \
  _Pragma("unroll") for (int q_=0; q_<NV; ++q_)                              \
    vh.q4[q_] = *(const uint4*)&smat[o*SSTR2 + q_*4];                        \
} while(0)

  const size_t ST = (size_t)NP*CD;
  const f16* pcur = ubase;
  LOADU(UA, pcur);
  for (int t=0; t<T; t+=2) {
    LOADU(UB, pcur + ST);          // tile t+1
    STEP(UA, t);
    LOADU(UA, pcur + 2*ST);        // tile t+2 (tail overread stays in ws)
    STEP(UB, t+1);
    pcur += 2*ST;
  }
#undef LOADU
#undef STEP
}

// ---------------------------------------------------------------- final: LN512 -> length -> LN32
__global__ __launch_bounds__(512) void k_final(
    const float* __restrict__ v1,
    const float* __restrict__ g1, const float* __restrict__ b1,
    const float* __restrict__ g2, const float* __restrict__ b2,
    float* __restrict__ out)
{
  int bt = blockIdx.x;
  int tid = threadIdx.x;
  float x = v1[(size_t)bt*512 + tid];
  __shared__ float red[16];
  __shared__ float Ls[32];
  float s1 = x, s2 = x*x;
#pragma unroll
  for (int m=1;m<64;m<<=1){ s1 += __shfl_xor(s1,m,64); s2 += __shfl_xor(s2,m,64); }
  if ((tid & 63) == 0){ red[(tid>>6)*2] = s1; red[(tid>>6)*2+1] = s2; }
  __syncthreads();
  float S1 = 0.f, S2 = 0.f;
#pragma unroll
  for (int i=0;i<8;i++){ S1 += red[2*i]; S2 += red[2*i+1]; }
  float mean = S1/512.f, var = S2/512.f - mean*mean;
  float y = (x-mean)*rsqrtf(var+1e-3f)*g1[tid] + b1[tid];
  float ss = y*y;
  ss += __shfl_xor(ss,1,16); ss += __shfl_xor(ss,2,16);
  ss += __shfl_xor(ss,4,16); ss += __shfl_xor(ss,8,16);
  float L = sqrtf(ss + 1e-9f);
  if ((tid & 15) == 0) Ls[tid >> 4] = L;
  __syncthreads();
  if (tid < 32) {
    float l = Ls[tid];
    float t1 = l, t2 = l*l;
#pragma unroll
    for (int m=1;m<32;m<<=1){ t1 += __shfl_xor(t1,m,32); t2 += __shfl_xor(t2,m,32); }
    float mn = t1/32.f, vr = t2/32.f - mn*mn;
    out[(size_t)bt*32 + tid] = (l-mn)*rsqrtf(vr+1e-3f)*g2[tid] + b2[tid];
  }
}

// ---------------------------------------------------------------- workspace layout
static const size_t OFF_X1F   = 0;            // 20,971,520 B f16 [4,1024,40,64]
static const size_t OFF_WT16  = 20971520;     //     77,824 B f16 [64][600]
static const size_t OFF_PWT   = 21049344;     //     40,960 B f16 [16][1280]
static const size_t OFF_X2F   = 21090304;     //  5,242,880 B f16 [2048][1280]
static const size_t OFF_EMB0  = 26333184;     //    131,072 B f32 [2048][16]
static const size_t OFF_UH0   = 26464256;     // 41,943,040 B f16 [4,512,1280,8]
static const size_t OFF_UH1   = 0;            // 167,772,160 B f16 [4,512,2560,16] (reuses dead frontend)
static const size_t OFF_EMBLN = 167772160;    //    524,288 B f16 [2048][128]
static const size_t OFF_V0    = 167772160;    //  1,048,576 B f32 (reuses EMBLN slot after uhat0)
static const size_t OFF_V0LN  = 168820736;    //    524,288 B f16
static const size_t OFF_V1    = 169869312;    //  4,194,304 B f32 [4,512,32,16]
static const size_t WS_NEED   = 174063616;

extern "C" void kernel_launch(void* const* d_in, const int* in_sizes, int n_in,
                              void* d_out, int out_size, void* d_ws, size_t ws_size,
                              hipStream_t stream) {
  (void)in_sizes; (void)n_in; (void)out_size;
  if (ws_size < WS_NEED) return;

  const float* inputs = (const float*)d_in[0];
  const int*   lens   = (const int*)d_in[1];
  const float* c1w=(const float*)d_in[2],  *c1b=(const float*)d_in[3];
  const float* c2w=(const float*)d_in[4],  *c2b=(const float*)d_in[5];
  const float* pw =(const float*)d_in[6],  *pb =(const float*)d_in[7];
  const float* e0w=(const float*)d_in[8],  *e0b=(const float*)d_in[9];
  const float* e1w=(const float*)d_in[10], *e1b=(const float*)d_in[11];
  const float* lnig=(const float*)d_in[12],*lnib=(const float*)d_in[13];
  const float* W0=(const float*)d_in[14],  *B0=(const float*)d_in[15];
  const float* W1=(const float*)d_in[16],  *B1=(const float*)d_in[17];
  const float* lnm0g=(const float*)d_in[18],*lnm0b=(const float*)d_in[19];
  const float* lnm1g=(const float*)d_in[20],*lnm1b=(const float*)d_in[21];
  const float* lnog=(const float*)d_in[22], *lnob=(const float*)d_in[23];

  char* ws = (char*)d_ws;
  f16*   x1f   = (f16*)  (ws + OFF_X1F);
  f16*   wt16  = (f16*)  (ws + OFF_WT16);
  f16*   pwT   = (f16*)  (ws + OFF_PWT);
  f16*   x2f   = (f16*)  (ws + OFF_X2F);
  float* emb0  = (float*)(ws + OFF_EMB0);
  f16*   uh0   = (f16*)  (ws + OFF_UH0);
  f16*   uh1   = (f16*)  (ws + OFF_UH1);
  f16*   embln = (f16*)  (ws + OFF_EMBLN);
  float* v0    = (float*)(ws + OFF_V0);
  f16*   v0ln  = (f16*)  (ws + OFF_V0LN);
  float* v1    = (float*)(ws + OFF_V1);

  k_conv1<<<40960, 256, 0, stream>>>(inputs, c1w, c1b, x1f);
  k_wcvt2<<<232, 256, 0, stream>>>(c2w, pw, wt16, pwT);
  k_conv2m<<<320, 256, 0, stream>>>(x1f, wt16, c2b, x2f);
  k_projm<<<32, 256, 0, stream>>>(x2f, pwT, pb, emb0);
  k_primary<<<2048, 128, 0, stream>>>(emb0, e0w, e0b, e1w, e1b, lnig, lnib, lens, embln);
  k_uhat2<16,8><<<160, 256, 0, stream>>>(embln, W0, B0, uh0);
  k_scan11<16,8,10,false><<<4, 640, 0, stream>>>(uh0, v0, 512);
  k_ln128<<<2048, 128, 0, stream>>>(v0, lnm0g, lnm0b, v0ln);
  k_uhat2<32,16><<<320, 256, 0, stream>>>(v0ln, W1, B1, uh1);
  k_scan11<32,16,8,true><<<4, 512, 0, stream>>>(uh1, v1, 512);
  k_final<<<2048, 512, 0, stream>>>(v1, lnm1g, lnm1b, lnog, lnob, (float*)d_out);
}